// Round 5
// baseline (348.147 us; speedup 1.0000x reference)
//
#include <hip/hip_runtime.h>

typedef __attribute__((ext_vector_type(8))) __bf16 bf16x8;
typedef __attribute__((ext_vector_type(4))) float f32x4;

#define B_ROWS 8192
#define D_DIM  1024
#define K_DIM  2048
#define NG     5120

typedef const __attribute__((address_space(1))) void cg_void;
typedef __attribute__((address_space(3))) void lds_void;

__device__ __forceinline__ float bf2f(unsigned short u) {
    union { unsigned int ui; float f; } c; c.ui = ((unsigned int)u) << 16; return c.f;
}
__device__ __forceinline__ unsigned short f2bf(float f) {
    unsigned int u = __float_as_uint(f);
    unsigned int r = u + 0x7fffu + ((u >> 16) & 1u);
    return (unsigned short)(r >> 16);
}
__device__ __forceinline__ float sigm(float v) { return 1.0f / (1.0f + __expf(-v)); }

// ---------------- weight f32 -> bf16 convert (both weights, one launch) ----------------
__global__ __launch_bounds__(256) void cvt2_f32_bf16(const float* __restrict__ wg,
                                                     const float* __restrict__ wu,
                                                     unsigned short* __restrict__ og,
                                                     unsigned short* __restrict__ ou) {
    const int NG4 = 5120 * 2048 / 4;
    const int NU4 = 1024 * 2048 / 4;
    int i = blockIdx.x * 256 + threadIdx.x;
    if (i < NG4) {
        float4 v = reinterpret_cast<const float4*>(wg)[i];
        ushort4 o; o.x = f2bf(v.x); o.y = f2bf(v.y); o.z = f2bf(v.z); o.w = f2bf(v.w);
        reinterpret_cast<ushort4*>(og)[i] = o;
    } else if (i < NG4 + NU4) {
        int j = i - NG4;
        float4 v = reinterpret_cast<const float4*>(wu)[j];
        ushort4 o; o.x = f2bf(v.x); o.y = f2bf(v.y); o.z = f2bf(v.z); o.w = f2bf(v.w);
        reinterpret_cast<ushort4*>(ou)[j] = o;
    }
}

// ---------------- LN1: concat(x,h) -> layernorm -> bf16 ----------------
__global__ __launch_bounds__(256) void ln1_kernel(const float* __restrict__ x, const float* __restrict__ h,
                                                  const float* __restrict__ w, const float* __restrict__ b,
                                                  unsigned short* __restrict__ out) {
    const int row = blockIdx.x;
    const int t = threadIdx.x;
    const float4 xv = reinterpret_cast<const float4*>(x + (size_t)row * D_DIM)[t];
    const float4 hv = reinterpret_cast<const float4*>(h + (size_t)row * D_DIM)[t];
    float s  = xv.x + xv.y + xv.z + xv.w + hv.x + hv.y + hv.z + hv.w;
    float s2 = xv.x*xv.x + xv.y*xv.y + xv.z*xv.z + xv.w*xv.w
             + hv.x*hv.x + hv.y*hv.y + hv.z*hv.z + hv.w*hv.w;
#pragma unroll
    for (int off = 32; off > 0; off >>= 1) { s += __shfl_xor(s, off); s2 += __shfl_xor(s2, off); }
    __shared__ float red[8];
    const int wid = t >> 6, lane = t & 63;
    if (lane == 0) { red[wid] = s; red[4 + wid] = s2; }
    __syncthreads();
    s  = red[0] + red[1] + red[2] + red[3];
    s2 = red[4] + red[5] + red[6] + red[7];
    const float mu  = s * (1.0f / K_DIM);
    const float var = s2 * (1.0f / K_DIM) - mu * mu;
    const float inv = rsqrtf(var + 1e-5f);
    const float4 w0 = reinterpret_cast<const float4*>(w)[t];
    const float4 b0 = reinterpret_cast<const float4*>(b)[t];
    const float4 w1 = reinterpret_cast<const float4*>(w + D_DIM)[t];
    const float4 b1 = reinterpret_cast<const float4*>(b + D_DIM)[t];
    ushort4 o0, o1;
    o0.x = f2bf((xv.x - mu) * inv * w0.x + b0.x);
    o0.y = f2bf((xv.y - mu) * inv * w0.y + b0.y);
    o0.z = f2bf((xv.z - mu) * inv * w0.z + b0.z);
    o0.w = f2bf((xv.w - mu) * inv * w0.w + b0.w);
    o1.x = f2bf((hv.x - mu) * inv * w1.x + b1.x);
    o1.y = f2bf((hv.y - mu) * inv * w1.y + b1.y);
    o1.z = f2bf((hv.z - mu) * inv * w1.z + b1.z);
    o1.w = f2bf((hv.w - mu) * inv * w1.w + b1.w);
    reinterpret_cast<ushort4*>(out + (size_t)row * K_DIM)[t] = o0;
    reinterpret_cast<ushort4*>(out + (size_t)row * K_DIM + D_DIM)[t] = o1;
}

// ---------------- gate sigmoid + LN2 -> bf16 inp2 ----------------
__global__ __launch_bounds__(256) void gate_ln2_kernel(const float* __restrict__ x, const float* __restrict__ h,
                                                       const unsigned short* __restrict__ gates,
                                                       const float* __restrict__ w, const float* __restrict__ b,
                                                       unsigned short* __restrict__ out) {
    const int row = blockIdx.x;
    const int t = threadIdx.x;
    const float4 xv = reinterpret_cast<const float4*>(x + (size_t)row * D_DIM)[t];
    const float4 hv = reinterpret_cast<const float4*>(h + (size_t)row * D_DIM)[t];
    const ushort4 g0v = reinterpret_cast<const ushort4*>(gates + (size_t)row * NG)[t];
    const ushort4 g1v = reinterpret_cast<const ushort4*>(gates + (size_t)row * NG + D_DIM)[t];
    float a0 = xv.x * sigm(bf2f(g0v.x));
    float a1 = xv.y * sigm(bf2f(g0v.y));
    float a2 = xv.z * sigm(bf2f(g0v.z));
    float a3 = xv.w * sigm(bf2f(g0v.w));
    float c0 = hv.x * sigm(bf2f(g1v.x));
    float c1 = hv.y * sigm(bf2f(g1v.y));
    float c2 = hv.z * sigm(bf2f(g1v.z));
    float c3 = hv.w * sigm(bf2f(g1v.w));
    float s  = a0 + a1 + a2 + a3 + c0 + c1 + c2 + c3;
    float s2 = a0*a0 + a1*a1 + a2*a2 + a3*a3 + c0*c0 + c1*c1 + c2*c2 + c3*c3;
#pragma unroll
    for (int off = 32; off > 0; off >>= 1) { s += __shfl_xor(s, off); s2 += __shfl_xor(s2, off); }
    __shared__ float red[8];
    const int wid = t >> 6, lane = t & 63;
    if (lane == 0) { red[wid] = s; red[4 + wid] = s2; }
    __syncthreads();
    s  = red[0] + red[1] + red[2] + red[3];
    s2 = red[4] + red[5] + red[6] + red[7];
    const float mu  = s * (1.0f / K_DIM);
    const float var = s2 * (1.0f / K_DIM) - mu * mu;
    const float inv = rsqrtf(var + 1e-5f);
    const float4 w0 = reinterpret_cast<const float4*>(w)[t];
    const float4 b0 = reinterpret_cast<const float4*>(b)[t];
    const float4 w1 = reinterpret_cast<const float4*>(w + D_DIM)[t];
    const float4 b1 = reinterpret_cast<const float4*>(b + D_DIM)[t];
    ushort4 o0, o1;
    o0.x = f2bf((a0 - mu) * inv * w0.x + b0.x);
    o0.y = f2bf((a1 - mu) * inv * w0.y + b0.y);
    o0.z = f2bf((a2 - mu) * inv * w0.z + b0.z);
    o0.w = f2bf((a3 - mu) * inv * w0.w + b0.w);
    o1.x = f2bf((c0 - mu) * inv * w1.x + b1.x);
    o1.y = f2bf((c1 - mu) * inv * w1.y + b1.y);
    o1.z = f2bf((c2 - mu) * inv * w1.z + b1.z);
    o1.w = f2bf((c3 - mu) * inv * w1.w + b1.w);
    reinterpret_cast<ushort4*>(out + (size_t)row * K_DIM)[t] = o0;
    reinterpret_cast<ushort4*>(out + (size_t)row * K_DIM + D_DIM)[t] = o1;
}

// ---------------- GEMM1: 128x256 tile, BK=32, 3-slot pipeline, 2 blocks/CU ----------------
// 512 thr = 8 waves (2M x 4N), wave = 64x64, acc = 4x4 f32x4 (64 VGPR).
// LDS 72KB: A 3 slots x 8KB + B 3 slots x 16KB -> 2 blocks/CU co-resident.
// Per phase (1 K-tile of 32): 8 ds_read_b128, stage next+2 K-tile (3 loads),
// vmcnt(3) (counted, never 0), 2 raw barriers, 16 MFMA under setprio.
// LDS layout: [lines of 128B], 2 tile-rows/line, XOR-swizzle byte^=((line&7)<<4)
// (involution applied on BOTH the pre-swizzled global source and the read addr).
#define VMC3 asm volatile("s_waitcnt vmcnt(3)" ::: "memory")

__global__ __launch_bounds__(512, 4) void gemm_gates_d1(const unsigned short* __restrict__ A,
                                                        const unsigned short* __restrict__ W,
                                                        const float* __restrict__ bias,
                                                        unsigned short* __restrict__ C) {
    constexpr int K = K_DIM;
    constexpr int NTK = K / 32;                 // 64 K-tiles
    extern __shared__ unsigned short smem[];    // A: [0,12288) B: [12288, 36864) ushorts

    const int tid = threadIdx.x;
    const int bid = blockIdx.x;                 // 1280 blocks (64 M x 20 N), %8==0
    const int swz = (bid & 7) * 160 + (bid >> 3);
    const int tm = swz / 20;
    const int tn = swz % 20;
    const int Arow0 = tm * 128;
    const int Brow0 = tn * 256;

    const int lane = tid & 63;
    const int wid = tid >> 6;
    const int wr = wid >> 2;        // 0..1 (M)
    const int wc = wid & 3;         // 0..3 (N)
    const int fr = lane & 15;
    const int kb = lane >> 4;

    // ds_read offsets (ushort idx within a slot), swizzled
    int aRd[4], bRd[4];
#pragma unroll
    for (int m = 0; m < 4; ++m) {
        const int row = wr * 64 + m * 16 + fr;
        aRd[m] = ((row >> 1) * 128 + ((((row & 1) * 64) + kb * 16) ^ (((row >> 1) & 7) << 4))) >> 1;
    }
#pragma unroll
    for (int n = 0; n < 4; ++n) {
        const int row = wc * 64 + n * 16 + fr;
        bRd[n] = ((row >> 1) * 128 + ((((row & 1) * 64) + kb * 16) ^ (((row >> 1) & 7) << 4))) >> 1;
    }

    // staging: linear LDS dest, inverse-swizzled global source (Rule 21)
    // A: 1 load/thread (8KB), B: 2 loads/thread (16KB)
    size_t aSrcB;
    {
        const int line = tid >> 3;
        const int inB = (tid & 7) * 16;
        const int inBS = inB ^ ((line & 7) << 4);
        const int row = line * 2 + (inBS >> 6);
        const int col = (inBS & 63) >> 1;
        aSrcB = (size_t)(Arow0 + row) * K + col;
    }
    size_t bSrcB[2];
#pragma unroll
    for (int l = 0; l < 2; ++l) {
        const int t2 = l * 512 + tid;
        const int line = t2 >> 3;
        const int inB = (t2 & 7) * 16;
        const int inBS = inB ^ ((line & 7) << 4);
        const int row = line * 2 + (inBS >> 6);
        const int col = (inBS & 63) >> 1;
        bSrcB[l] = (size_t)(Brow0 + row) * K + col;
    }

    auto stageA = [&](int slot, int kt) {
        __builtin_amdgcn_global_load_lds((cg_void*)(A + aSrcB + kt * 32),
                                         (lds_void*)(&smem[slot * 4096 + tid * 8]), 16, 0, 0);
    };
    auto stageB = [&](int slot, int kt) {
#pragma unroll
        for (int l = 0; l < 2; ++l)
            __builtin_amdgcn_global_load_lds((cg_void*)(W + bSrcB[l] + kt * 32),
                                             (lds_void*)(&smem[12288 + slot * 8192 + (l * 512 + tid) * 8]), 16, 0, 0);
    };

    f32x4 acc[4][4] = {};

    // prologue: K-tiles 0,1 into slots 0,1 (6 loads); wait tile0 (vmcnt(3))
    stageA(0, 0); stageB(0, 0);
    stageA(1, 1); stageB(1, 1);
    VMC3;
    asm volatile("" ::: "memory");
    __builtin_amdgcn_s_barrier();
    asm volatile("" ::: "memory");

    int sC = 0;                                 // slot of current K-tile
    for (int t = 0; t < NTK; ++t) {
        const int sP = (sC == 0) ? 2 : sC - 1;  // slot of K-tile t+2
        const int kt2 = (t + 2) & (NTK - 1);

        bf16x8 aF[4], bF[4];
#pragma unroll
        for (int m = 0; m < 4; ++m)
            aF[m] = *reinterpret_cast<const bf16x8*>(&smem[sC * 4096 + aRd[m]]);
#pragma unroll
        for (int n = 0; n < 4; ++n)
            bF[n] = *reinterpret_cast<const bf16x8*>(&smem[12288 + sC * 8192 + bRd[n]]);

        stageA(sP, kt2);
        stageB(sP, kt2);
        VMC3;                                   // (t+1)'s 3 loads landed; (t+2)'s stay in flight
        asm volatile("" ::: "memory");
        __builtin_amdgcn_s_barrier();
        asm volatile("" ::: "memory");

        __builtin_amdgcn_s_setprio(1);
#pragma unroll
        for (int m = 0; m < 4; ++m)
#pragma unroll
            for (int n = 0; n < 4; ++n)
                acc[m][n] = __builtin_amdgcn_mfma_f32_16x16x32_bf16(aF[m], bF[n], acc[m][n], 0, 0, 0);
        __builtin_amdgcn_s_setprio(0);
        asm volatile("" ::: "memory");
        __builtin_amdgcn_s_barrier();
        asm volatile("" ::: "memory");

        sC = (sC == 2) ? 0 : sC + 1;
    }

    // epilogue: bias + bf16 store
    const int crow0 = Arow0 + wr * 64;
    const int ccol = Brow0 + wc * 64;
#pragma unroll
    for (int n = 0; n < 4; ++n) {
        const int c = ccol + n * 16 + fr;
        const float bvv = bias[c];
#pragma unroll
        for (int m = 0; m < 4; ++m) {
            const size_t r0 = (size_t)crow0 + m * 16 + kb * 4;
#pragma unroll
            for (int j = 0; j < 4; ++j)
                C[(r0 + j) * NG + c] = f2bf(acc[m][n][j] + bvv);
        }
    }
}

// ---------------- GEMM2 + fused epilogue: h_new ----------------
__global__ __launch_bounds__(256) void gemm_out(const unsigned short* __restrict__ A,     // inp2 [8192][2048]
                                                const unsigned short* __restrict__ W,     // Wu  [1024][2048]
                                                const float* __restrict__ bias,           // bu [1024]
                                                const unsigned short* __restrict__ gates, // [8192][5120]
                                                const float* __restrict__ x, const float* __restrict__ h,
                                                float* __restrict__ out) {                // [8192][1024]
    constexpr int K = K_DIM, N = D_DIM;
    __shared__ __attribute__((aligned(16))) unsigned short As[2][128 * 32];
    __shared__ __attribute__((aligned(16))) unsigned short Bs[2][128 * 32];
    const int tid = threadIdx.x;
    const int bid = blockIdx.x;                  // 512 blocks
    const int swz = (bid & 7) * 64 + (bid >> 3);
    const int tn = swz & 7;
    const int tm = swz >> 3;
    const size_t arow0 = (size_t)tm * 128;
    const size_t brow0 = (size_t)tn * 128;

    const int lane = tid & 63;
    const int wid = tid >> 6;
    const int wr = wid >> 1, wc = wid & 1;
    const int fr = lane & 15;
    const int kb = lane >> 4;
    const int aoff = (wr * 64 + fr) * 32 + kb * 8;
    const int boff = (wc * 64 + fr) * 32 + kb * 8;

    f32x4 acc[4][4] = {};

    auto stage = [&](int buf, int k0) {
#pragma unroll
        for (int r = 0; r < 2; ++r) {
            const int idx = r * 256 + tid;
            __builtin_amdgcn_global_load_lds(
                (cg_void*)(A + (arow0 + (idx >> 2)) * K + k0 + (idx & 3) * 8),
                (lds_void*)(&As[buf][idx * 8]), 16, 0, 0);
        }
#pragma unroll
        for (int r = 0; r < 2; ++r) {
            const int idx = r * 256 + tid;
            __builtin_amdgcn_global_load_lds(
                (cg_void*)(W + (brow0 + (idx >> 2)) * K + k0 + (idx & 3) * 8),
                (lds_void*)(&Bs[buf][idx * 8]), 16, 0, 0);
        }
    };

    stage(0, 0);
    __syncthreads();
    int cur = 0;
    constexpr int NT = K / 32;
    for (int t = 0; t < NT; ++t) {
        if (t + 1 < NT) stage(cur ^ 1, (t + 1) * 32);
        bf16x8 af[4], bv[4];
#pragma unroll
        for (int m = 0; m < 4; ++m) af[m] = *reinterpret_cast<const bf16x8*>(&As[cur][aoff + m * 512]);
#pragma unroll
        for (int n = 0; n < 4; ++n) bv[n] = *reinterpret_cast<const bf16x8*>(&Bs[cur][boff + n * 512]);
#pragma unroll
        for (int m = 0; m < 4; ++m)
#pragma unroll
            for (int n = 0; n < 4; ++n)
                acc[m][n] = __builtin_amdgcn_mfma_f32_16x16x32_bf16(af[m], bv[n], acc[m][n], 0, 0, 0);
        __syncthreads();
        cur ^= 1;
    }

    const size_t crow0 = arow0 + wr * 64;
    const int ccol0 = (int)brow0 + wc * 64;
#pragma unroll
    for (int n = 0; n < 4; ++n) {
        const int c = ccol0 + n * 16 + fr;
        const float bvv = bias[c];
#pragma unroll
        for (int m = 0; m < 4; ++m) {
            const size_t r0 = crow0 + m * 16 + kb * 4;
#pragma unroll
            for (int j = 0; j < 4; ++j) {
                const size_t r = r0 + j;
                const float u = tanhf(acc[m][n][j] + bvv);
                const size_t gb = r * NG + c;
                const float g2 = bf2f(gates[gb + 2 * D_DIM]);
                const float g3 = bf2f(gates[gb + 3 * D_DIM]);
                const float g4 = bf2f(gates[gb + 4 * D_DIM]);
                const float mx = fmaxf(fmaxf(g2, g3), g4);
                const float e2 = __expf(g2 - mx), e3 = __expf(g3 - mx), e4 = __expf(g4 - mx);
                const float zi = 1.0f / (e2 + e3 + e4);
                const size_t xi = r * D_DIM + c;
                out[xi] = (x[xi] * e2 + h[xi] * e3 + u * e4) * zi;
            }
        }
    }
}

extern "C" void kernel_launch(void* const* d_in, const int* in_sizes, int n_in,
                              void* d_out, int out_size, void* d_ws, size_t ws_size,
                              hipStream_t stream) {
    const float* x    = (const float*)d_in[0];
    const float* h    = (const float*)d_in[1];
    const float* ln_w = (const float*)d_in[2];
    const float* ln_b = (const float*)d_in[3];
    const float* ln2_w= (const float*)d_in[4];
    const float* ln2_b= (const float*)d_in[5];
    const float* Wg   = (const float*)d_in[6];
    const float* bg   = (const float*)d_in[7];
    const float* Wu   = (const float*)d_in[8];
    const float* bu   = (const float*)d_in[9];
    float* out = (float*)d_out;

    char* ws = (char*)d_ws;
    unsigned short* inp   = (unsigned short*)(ws);                                   // [8192][2048] (reused as inp2)
    unsigned short* Wg_b  = (unsigned short*)(ws + 33554432);                        // [5120][2048]
    unsigned short* Wu_b  = (unsigned short*)(ws + 33554432 + 20971520);             // [1024][2048]
    unsigned short* gates = (unsigned short*)(ws + 33554432 + 20971520 + 4194304);   // [8192][5120]

    (void)hipFuncSetAttribute((const void*)gemm_gates_d1,
                              hipFuncAttributeMaxDynamicSharedMemorySize, 73728);

    const int nCvt4 = 5120 * 2048 / 4 + 1024 * 2048 / 4;
    cvt2_f32_bf16<<<(nCvt4 + 255) / 256, 256, 0, stream>>>(Wg, Wu, Wg_b, Wu_b);
    ln1_kernel<<<8192, 256, 0, stream>>>(x, h, ln_w, ln_b, inp);
    gemm_gates_d1<<<1280, 512, 73728, stream>>>(inp, Wg_b, bg, gates);
    gate_ln2_kernel<<<8192, 256, 0, stream>>>(x, h, gates, ln2_w, ln2_b, inp);
    gemm_out<<<512, 256, 0, stream>>>(inp, Wu_b, bu, gates, x, h, out);
}

// Round 6
// 320.028 us; speedup vs baseline: 1.0879x; 1.0879x over previous
//
#include <hip/hip_runtime.h>

typedef __attribute__((ext_vector_type(8))) __bf16 bf16x8;
typedef __attribute__((ext_vector_type(4))) float f32x4;

#define B_ROWS 8192
#define D_DIM  1024
#define K_DIM  2048
#define NG     5120

typedef const __attribute__((address_space(1))) void cg_void;
typedef __attribute__((address_space(3))) void lds_void;

__device__ __forceinline__ float bf2f(unsigned short u) {
    union { unsigned int ui; float f; } c; c.ui = ((unsigned int)u) << 16; return c.f;
}
__device__ __forceinline__ unsigned short f2bf(float f) {
    unsigned int u = __float_as_uint(f);
    unsigned int r = u + 0x7fffu + ((u >> 16) & 1u);
    return (unsigned short)(r >> 16);
}
__device__ __forceinline__ float sigm(float v) { return 1.0f / (1.0f + __expf(-v)); }

// ---------------- weight f32 -> bf16 convert (both weights, one launch) ----------------
__global__ __launch_bounds__(256) void cvt2_f32_bf16(const float* __restrict__ wg,
                                                     const float* __restrict__ wu,
                                                     unsigned short* __restrict__ og,
                                                     unsigned short* __restrict__ ou) {
    const int NG4 = 5120 * 2048 / 4;
    const int NU4 = 1024 * 2048 / 4;
    int i = blockIdx.x * 256 + threadIdx.x;
    if (i < NG4) {
        float4 v = reinterpret_cast<const float4*>(wg)[i];
        ushort4 o; o.x = f2bf(v.x); o.y = f2bf(v.y); o.z = f2bf(v.z); o.w = f2bf(v.w);
        reinterpret_cast<ushort4*>(og)[i] = o;
    } else if (i < NG4 + NU4) {
        int j = i - NG4;
        float4 v = reinterpret_cast<const float4*>(wu)[j];
        ushort4 o; o.x = f2bf(v.x); o.y = f2bf(v.y); o.z = f2bf(v.z); o.w = f2bf(v.w);
        reinterpret_cast<ushort4*>(ou)[j] = o;
    }
}

// ---------------- LN1: concat(x,h) -> layernorm -> bf16 ----------------
__global__ __launch_bounds__(256) void ln1_kernel(const float* __restrict__ x, const float* __restrict__ h,
                                                  const float* __restrict__ w, const float* __restrict__ b,
                                                  unsigned short* __restrict__ out) {
    const int row = blockIdx.x;
    const int t = threadIdx.x;
    const float4 xv = reinterpret_cast<const float4*>(x + (size_t)row * D_DIM)[t];
    const float4 hv = reinterpret_cast<const float4*>(h + (size_t)row * D_DIM)[t];
    float s  = xv.x + xv.y + xv.z + xv.w + hv.x + hv.y + hv.z + hv.w;
    float s2 = xv.x*xv.x + xv.y*xv.y + xv.z*xv.z + xv.w*xv.w
             + hv.x*hv.x + hv.y*hv.y + hv.z*hv.z + hv.w*hv.w;
#pragma unroll
    for (int off = 32; off > 0; off >>= 1) { s += __shfl_xor(s, off); s2 += __shfl_xor(s2, off); }
    __shared__ float red[8];
    const int wid = t >> 6, lane = t & 63;
    if (lane == 0) { red[wid] = s; red[4 + wid] = s2; }
    __syncthreads();
    s  = red[0] + red[1] + red[2] + red[3];
    s2 = red[4] + red[5] + red[6] + red[7];
    const float mu  = s * (1.0f / K_DIM);
    const float var = s2 * (1.0f / K_DIM) - mu * mu;
    const float inv = rsqrtf(var + 1e-5f);
    const float4 w0 = reinterpret_cast<const float4*>(w)[t];
    const float4 b0 = reinterpret_cast<const float4*>(b)[t];
    const float4 w1 = reinterpret_cast<const float4*>(w + D_DIM)[t];
    const float4 b1 = reinterpret_cast<const float4*>(b + D_DIM)[t];
    ushort4 o0, o1;
    o0.x = f2bf((xv.x - mu) * inv * w0.x + b0.x);
    o0.y = f2bf((xv.y - mu) * inv * w0.y + b0.y);
    o0.z = f2bf((xv.z - mu) * inv * w0.z + b0.z);
    o0.w = f2bf((xv.w - mu) * inv * w0.w + b0.w);
    o1.x = f2bf((hv.x - mu) * inv * w1.x + b1.x);
    o1.y = f2bf((hv.y - mu) * inv * w1.y + b1.y);
    o1.z = f2bf((hv.z - mu) * inv * w1.z + b1.z);
    o1.w = f2bf((hv.w - mu) * inv * w1.w + b1.w);
    reinterpret_cast<ushort4*>(out + (size_t)row * K_DIM)[t] = o0;
    reinterpret_cast<ushort4*>(out + (size_t)row * K_DIM + D_DIM)[t] = o1;
}

// ---------------- gate sigmoid + LN2 -> bf16 inp2 ----------------
__global__ __launch_bounds__(256) void gate_ln2_kernel(const float* __restrict__ x, const float* __restrict__ h,
                                                       const unsigned short* __restrict__ gates,
                                                       const float* __restrict__ w, const float* __restrict__ b,
                                                       unsigned short* __restrict__ out) {
    const int row = blockIdx.x;
    const int t = threadIdx.x;
    const float4 xv = reinterpret_cast<const float4*>(x + (size_t)row * D_DIM)[t];
    const float4 hv = reinterpret_cast<const float4*>(h + (size_t)row * D_DIM)[t];
    const ushort4 g0v = reinterpret_cast<const ushort4*>(gates + (size_t)row * NG)[t];
    const ushort4 g1v = reinterpret_cast<const ushort4*>(gates + (size_t)row * NG + D_DIM)[t];
    float a0 = xv.x * sigm(bf2f(g0v.x));
    float a1 = xv.y * sigm(bf2f(g0v.y));
    float a2 = xv.z * sigm(bf2f(g0v.z));
    float a3 = xv.w * sigm(bf2f(g0v.w));
    float c0 = hv.x * sigm(bf2f(g1v.x));
    float c1 = hv.y * sigm(bf2f(g1v.y));
    float c2 = hv.z * sigm(bf2f(g1v.z));
    float c3 = hv.w * sigm(bf2f(g1v.w));
    float s  = a0 + a1 + a2 + a3 + c0 + c1 + c2 + c3;
    float s2 = a0*a0 + a1*a1 + a2*a2 + a3*a3 + c0*c0 + c1*c1 + c2*c2 + c3*c3;
#pragma unroll
    for (int off = 32; off > 0; off >>= 1) { s += __shfl_xor(s, off); s2 += __shfl_xor(s2, off); }
    __shared__ float red[8];
    const int wid = t >> 6, lane = t & 63;
    if (lane == 0) { red[wid] = s; red[4 + wid] = s2; }
    __syncthreads();
    s  = red[0] + red[1] + red[2] + red[3];
    s2 = red[4] + red[5] + red[6] + red[7];
    const float mu  = s * (1.0f / K_DIM);
    const float var = s2 * (1.0f / K_DIM) - mu * mu;
    const float inv = rsqrtf(var + 1e-5f);
    const float4 w0 = reinterpret_cast<const float4*>(w)[t];
    const float4 b0 = reinterpret_cast<const float4*>(b)[t];
    const float4 w1 = reinterpret_cast<const float4*>(w + D_DIM)[t];
    const float4 b1 = reinterpret_cast<const float4*>(b + D_DIM)[t];
    ushort4 o0, o1;
    o0.x = f2bf((a0 - mu) * inv * w0.x + b0.x);
    o0.y = f2bf((a1 - mu) * inv * w0.y + b0.y);
    o0.z = f2bf((a2 - mu) * inv * w0.z + b0.z);
    o0.w = f2bf((a3 - mu) * inv * w0.w + b0.w);
    o1.x = f2bf((c0 - mu) * inv * w1.x + b1.x);
    o1.y = f2bf((c1 - mu) * inv * w1.y + b1.y);
    o1.z = f2bf((c2 - mu) * inv * w1.z + b1.z);
    o1.w = f2bf((c3 - mu) * inv * w1.w + b1.w);
    reinterpret_cast<ushort4*>(out + (size_t)row * K_DIM)[t] = o0;
    reinterpret_cast<ushort4*>(out + (size_t)row * K_DIM + D_DIM)[t] = o1;
}

// ---------------- GEMM1: 256x256 8-phase pipelined (round-2 race-verified) ----------------
#define PH(BUF, H, KQ, LOADB, STAGE_CODE, VMCNT_CODE) do {                                            \
    bf16x8 aF[4];                                                                                     \
    _Pragma("unroll")                                                                                 \
    for (int m = 0; m < 4; ++m)                                                                       \
        aF[m] = *reinterpret_cast<const bf16x8*>(                                                     \
            &smem[((BUF) * 2 + (H)) * 8192 + ((aRdS[m] ^ ((KQ) * 64)) >> 1)]);                        \
    if (LOADB) {                                                                                      \
        _Pragma("unroll")                                                                             \
        for (int n = 0; n < 4; ++n)                                                                   \
            bF[KQ][n] = *reinterpret_cast<const bf16x8*>(                                             \
                &smem[32768 + ((BUF) * 2 + bHalf) * 8192 + ((bRdS[n] ^ ((KQ) * 64)) >> 1)]);          \
    }                                                                                                 \
    STAGE_CODE;                                                                                       \
    VMCNT_CODE;                                                                                       \
    asm volatile("" ::: "memory");                                                                    \
    __builtin_amdgcn_s_barrier();                                                                     \
    asm volatile("" ::: "memory");                                                                    \
    __builtin_amdgcn_s_setprio(1);                                                                    \
    _Pragma("unroll")                                                                                 \
    for (int m = 0; m < 4; ++m)                                                                       \
        _Pragma("unroll")                                                                             \
        for (int n = 0; n < 4; ++n)                                                                   \
            acc[(H) * 4 + m][n] =                                                                     \
                __builtin_amdgcn_mfma_f32_16x16x32_bf16(aF[m], bF[KQ][n], acc[(H) * 4 + m][n], 0, 0, 0);\
    __builtin_amdgcn_s_setprio(0);                                                                    \
    asm volatile("" ::: "memory");                                                                    \
    __builtin_amdgcn_s_barrier();                                                                     \
    asm volatile("" ::: "memory");                                                                    \
} while (0)

#define VMC4 asm volatile("s_waitcnt vmcnt(4)" ::: "memory")
#define NOVM (void)0

__global__ __launch_bounds__(512, 2) void gemm_gates8(const unsigned short* __restrict__ A,
                                                      const unsigned short* __restrict__ W,
                                                      const float* __restrict__ bias,
                                                      unsigned short* __restrict__ C) {
    constexpr int K = K_DIM;
    constexpr int NT = K / 64;       // 32 K-tiles
    constexpr int NI = NT / 2;       // 16 iterations
    extern __shared__ unsigned short smem[];   // A: [0,32768) B: [32768,65536) ushorts

    const int tid = threadIdx.x;
    const int bid = blockIdx.x;                 // 640 blocks (32 x 20), %8==0
    const int swz = (bid & 7) * 80 + (bid >> 3);
    const int tm = swz / 20;
    const int tn = swz % 20;
    const int Arow0 = tm * 256;
    const int Brow0 = tn * 256;

    const int lane = tid & 63;
    const int wid = tid >> 6;
    const int wr = wid >> 2;        // 0..1 (M)
    const int wc = wid & 3;         // 0..3 (N)
    const int fr = lane & 15;
    const int kb = lane >> 4;
    const int bHalf = wc >> 1;
    const int swzl = (fr & 7) << 4;

    int aRdS[4], bRdS[4];
#pragma unroll
    for (int m = 0; m < 4; ++m)
        aRdS[m] = (((wr * 64 + m * 16 + fr) * 128) + kb * 16) ^ swzl;
#pragma unroll
    for (int n = 0; n < 4; ++n)
        bRdS[n] = ((((wc & 1) * 64 + n * 16 + fr) * 128) + kb * 16) ^ swzl;

    size_t aSrc[2], bSrc[2];
    int ldsDst[2];
#pragma unroll
    for (int l = 0; l < 2; ++l) {
        const int off = (l * 512 + tid) * 16;       // byte off within a 16KB half
        const int r = off >> 7;                     // row 0..127
        const int offS = off ^ ((r & 7) << 4);
        const int cb = (offS & 127) >> 1;           // element col 0..63
        aSrc[l] = (size_t)(Arow0 + r) * K + cb;
        bSrc[l] = (size_t)(Brow0 + r) * K + cb;
        ldsDst[l] = (l * 512 + tid) * 8;            // ushort idx within a half
    }

    auto stageA = [&](int buf, int half, int kt) {
#pragma unroll
        for (int l = 0; l < 2; ++l)
            __builtin_amdgcn_global_load_lds(
                (cg_void*)(A + aSrc[l] + (size_t)half * 128 * K + kt * 64),
                (lds_void*)(&smem[(buf * 2 + half) * 8192 + ldsDst[l]]), 16, 0, 0);
    };
    auto stageB = [&](int buf, int half, int kt) {
#pragma unroll
        for (int l = 0; l < 2; ++l)
            __builtin_amdgcn_global_load_lds(
                (cg_void*)(W + bSrc[l] + (size_t)half * 128 * K + kt * 64),
                (lds_void*)(&smem[32768 + (buf * 2 + half) * 8192 + ldsDst[l]]), 16, 0, 0);
    };

    f32x4 acc[8][4] = {};

    stageA(0, 0, 0); stageA(0, 1, 0); stageB(0, 0, 0); stageB(0, 1, 0);
    stageB(1, 0, 1); stageB(1, 1, 1);
    VMC4;
    asm volatile("" ::: "memory");
    __builtin_amdgcn_s_barrier();
    asm volatile("" ::: "memory");

    for (int i = 0; i < NI; ++i) {
        const int t1 = 2 * i + 1;
        const int t2 = (2 * i + 2) & (NT - 1);
        const int t3 = (2 * i + 3) & (NT - 1);
        bf16x8 bF[2][4];
        PH(0, 0, 0, 1, { stageA(1, 0, t1); stageA(1, 1, t1); }, NOVM);   // P1
        PH(0, 0, 1, 1, ;, NOVM);                                          // P2
        PH(0, 1, 0, 0, { stageA(0, 0, t2); }, NOVM);                      // P3
        PH(0, 1, 1, 0, { stageB(0, 0, t2); }, VMC4);                      // P4
        PH(1, 0, 0, 1, { stageA(0, 1, t2); stageB(0, 1, t2); }, NOVM);    // P5
        PH(1, 0, 1, 1, ;, NOVM);                                          // P6
        PH(1, 1, 0, 0, { stageB(1, 0, t3); }, NOVM);                      // P7
        PH(1, 1, 1, 0, { stageB(1, 1, t3); }, VMC4);                      // P8
    }

    const int crowBase = Arow0 + wr * 64;
    const int ccol = Brow0 + wc * 64;
#pragma unroll
    for (int n = 0; n < 4; ++n) {
        const int c = ccol + n * 16 + fr;
        const float bvv = bias[c];
#pragma unroll
        for (int hh = 0; hh < 2; ++hh)
#pragma unroll
            for (int m = 0; m < 4; ++m) {
                const size_t r0 = (size_t)crowBase + hh * 128 + m * 16 + kb * 4;
#pragma unroll
                for (int j = 0; j < 4; ++j)
                    C[(r0 + j) * NG + c] = f2bf(acc[hh * 4 + m][n][j] + bvv);
            }
    }
}

// ---------------- GEMM2: 128x128, 3-slot counted-vmcnt pipeline (R5-verified scheme),
// all 512 blocks co-resident (2/CU, capacity 3/CU), fused tanh/softmax/h_new epilogue ----
__global__ __launch_bounds__(256, 3) void gemm_out3(const unsigned short* __restrict__ A,   // inp2 [8192][2048]
                                                    const unsigned short* __restrict__ W,   // Wu [1024][2048]
                                                    const float* __restrict__ bias,         // bu [1024]
                                                    const unsigned short* __restrict__ gates,
                                                    const float* __restrict__ x, const float* __restrict__ h,
                                                    float* __restrict__ out) {
    constexpr int K = K_DIM;
    constexpr int NTK = K / 32;                 // 64 K-tiles
    extern __shared__ unsigned short smem[];    // A: 3 x 4096 ushorts [0,12288); B: [12288,24576)

    const int tid = threadIdx.x;
    const int bid = blockIdx.x;                 // 512 blocks (64 M x 8 N), %8==0
    const int swz = (bid & 7) * 64 + (bid >> 3);
    const int tn = swz & 7;
    const int tm = swz >> 3;
    const int Arow0 = tm * 128;
    const int Brow0 = tn * 128;

    const int lane = tid & 63;
    const int wid = tid >> 6;
    const int wr = wid >> 1;        // 0..1 (M)
    const int wc = wid & 1;         // 0..1 (N)
    const int fr = lane & 15;
    const int kb = lane >> 4;

    // ds_read offsets (ushort idx within a slot), XOR-swizzled (R5 formula)
    int aRd[4], bRd[4];
#pragma unroll
    for (int m = 0; m < 4; ++m) {
        const int row = wr * 64 + m * 16 + fr;
        aRd[m] = ((row >> 1) * 128 + ((((row & 1) * 64) + kb * 16) ^ (((row >> 1) & 7) << 4))) >> 1;
    }
#pragma unroll
    for (int n = 0; n < 4; ++n) {
        const int row = wc * 64 + n * 16 + fr;
        bRd[n] = ((row >> 1) * 128 + ((((row & 1) * 64) + kb * 16) ^ (((row >> 1) & 7) << 4))) >> 1;
    }

    // staging: linear LDS dest, inverse-swizzled global source (Rule 21); 2 loads/thread/operand
    size_t aSrcB[2], bSrcB[2];
#pragma unroll
    for (int l = 0; l < 2; ++l) {
        const int t2 = l * 256 + tid;
        const int line = t2 >> 3;
        const int inB = (t2 & 7) * 16;
        const int inBS = inB ^ ((line & 7) << 4);
        const int row = line * 2 + (inBS >> 6);
        const int col = (inBS & 63) >> 1;
        aSrcB[l] = (size_t)(Arow0 + row) * K + col;
        bSrcB[l] = (size_t)(Brow0 + row) * K + col;
    }

    auto stage = [&](int slot, int kt) {
#pragma unroll
        for (int l = 0; l < 2; ++l)
            __builtin_amdgcn_global_load_lds((cg_void*)(A + aSrcB[l] + kt * 32),
                                             (lds_void*)(&smem[slot * 4096 + (l * 256 + tid) * 8]), 16, 0, 0);
#pragma unroll
        for (int l = 0; l < 2; ++l)
            __builtin_amdgcn_global_load_lds((cg_void*)(W + bSrcB[l] + kt * 32),
                                             (lds_void*)(&smem[12288 + slot * 4096 + (l * 256 + tid) * 8]), 16, 0, 0);
    };

    f32x4 acc[4][4] = {};

    // prologue: K-tiles 0,1 into slots 0,1 (8 loads); wait tile0 (vmcnt(4))
    stage(0, 0); stage(1, 1);
    VMC4;
    asm volatile("" ::: "memory");
    __builtin_amdgcn_s_barrier();
    asm volatile("" ::: "memory");

    int sC = 0;
    for (int t = 0; t < NTK; ++t) {
        const int sP = (sC == 0) ? 2 : sC - 1;
        const int kt2 = (t + 2) & (NTK - 1);

        bf16x8 aF[4], bF[4];
#pragma unroll
        for (int m = 0; m < 4; ++m)
            aF[m] = *reinterpret_cast<const bf16x8*>(&smem[sC * 4096 + aRd[m]]);
#pragma unroll
        for (int n = 0; n < 4; ++n)
            bF[n] = *reinterpret_cast<const bf16x8*>(&smem[12288 + sC * 4096 + bRd[n]]);

        stage(sP, kt2);
        VMC4;                                   // t+1's 4 loads landed; t+2's stay in flight
        asm volatile("" ::: "memory");
        __builtin_amdgcn_s_barrier();
        asm volatile("" ::: "memory");

        __builtin_amdgcn_s_setprio(1);
#pragma unroll
        for (int m = 0; m < 4; ++m)
#pragma unroll
            for (int n = 0; n < 4; ++n)
                acc[m][n] = __builtin_amdgcn_mfma_f32_16x16x32_bf16(aF[m], bF[n], acc[m][n], 0, 0, 0);
        __builtin_amdgcn_s_setprio(0);
        asm volatile("" ::: "memory");
        __builtin_amdgcn_s_barrier();
        asm volatile("" ::: "memory");

        sC = (sC == 2) ? 0 : sC + 1;
    }

    // fused epilogue: u = tanh(acc+bu); z = softmax(g2,g3,g4); h_new
    const int crow0 = Arow0 + wr * 64;
    const int ccol0 = Brow0 + wc * 64;
#pragma unroll
    for (int n = 0; n < 4; ++n) {
        const int c = ccol0 + n * 16 + fr;
        const float bvv = bias[c];
#pragma unroll
        for (int m = 0; m < 4; ++m) {
            const size_t r0 = (size_t)crow0 + m * 16 + kb * 4;
#pragma unroll
            for (int j = 0; j < 4; ++j) {
                const size_t r = r0 + j;
                const float u = tanhf(acc[m][n][j] + bvv);
                const size_t gb = r * NG + c;
                const float g2 = bf2f(gates[gb + 2 * D_DIM]);
                const float g3 = bf2f(gates[gb + 3 * D_DIM]);
                const float g4 = bf2f(gates[gb + 4 * D_DIM]);
                const float mx = fmaxf(fmaxf(g2, g3), g4);
                const float e2 = __expf(g2 - mx), e3 = __expf(g3 - mx), e4 = __expf(g4 - mx);
                const float zi = 1.0f / (e2 + e3 + e4);
                const size_t xi = r * D_DIM + c;
                out[xi] = (x[xi] * e2 + h[xi] * e3 + u * e4) * zi;
            }
        }
    }
}

extern "C" void kernel_launch(void* const* d_in, const int* in_sizes, int n_in,
                              void* d_out, int out_size, void* d_ws, size_t ws_size,
                              hipStream_t stream) {
    const float* x    = (const float*)d_in[0];
    const float* h    = (const float*)d_in[1];
    const float* ln_w = (const float*)d_in[2];
    const float* ln_b = (const float*)d_in[3];
    const float* ln2_w= (const float*)d_in[4];
    const float* ln2_b= (const float*)d_in[5];
    const float* Wg   = (const float*)d_in[6];
    const float* bg   = (const float*)d_in[7];
    const float* Wu   = (const float*)d_in[8];
    const float* bu   = (const float*)d_in[9];
    float* out = (float*)d_out;

    char* ws = (char*)d_ws;
    unsigned short* inp   = (unsigned short*)(ws);                                   // [8192][2048] (reused as inp2)
    unsigned short* Wg_b  = (unsigned short*)(ws + 33554432);                        // [5120][2048]
    unsigned short* Wu_b  = (unsigned short*)(ws + 33554432 + 20971520);             // [1024][2048]
    unsigned short* gates = (unsigned short*)(ws + 33554432 + 20971520 + 4194304);   // [8192][5120]

    (void)hipFuncSetAttribute((const void*)gemm_gates8,
                              hipFuncAttributeMaxDynamicSharedMemorySize, 131072);
    (void)hipFuncSetAttribute((const void*)gemm_out3,
                              hipFuncAttributeMaxDynamicSharedMemorySize, 49152);

    const int nCvt4 = 5120 * 2048 / 4 + 1024 * 2048 / 4;
    cvt2_f32_bf16<<<(nCvt4 + 255) / 256, 256, 0, stream>>>(Wg, Wu, Wg_b, Wu_b);
    ln1_kernel<<<8192, 256, 0, stream>>>(x, h, ln_w, ln_b, inp);
    gemm_gates8<<<640, 512, 131072, stream>>>(inp, Wg_b, bg, gates);
    gate_ln2_kernel<<<8192, 256, 0, stream>>>(x, h, gates, ln2_w, ln2_b, inp);
    gemm_out3<<<512, 256, 49152, stream>>>(inp, Wu_b, bu, gates, x, h, out);
}

// Round 7
// 316.916 us; speedup vs baseline: 1.0985x; 1.0098x over previous
//
#include <hip/hip_runtime.h>

typedef __attribute__((ext_vector_type(8))) __bf16 bf16x8;
typedef __attribute__((ext_vector_type(4))) float f32x4;

#define B_ROWS 8192
#define D_DIM  1024
#define K_DIM  2048
#define NG     5120

typedef const __attribute__((address_space(1))) void cg_void;
typedef __attribute__((address_space(3))) void lds_void;

__device__ __forceinline__ float bf2f(unsigned short u) {
    union { unsigned int ui; float f; } c; c.ui = ((unsigned int)u) << 16; return c.f;
}
__device__ __forceinline__ unsigned short f2bf(float f) {
    unsigned int u = __float_as_uint(f);
    unsigned int r = u + 0x7fffu + ((u >> 16) & 1u);
    return (unsigned short)(r >> 16);
}
__device__ __forceinline__ float sigm(float v) { return 1.0f / (1.0f + __expf(-v)); }

// ---------------- weight f32 -> bf16 convert (both weights, one launch) ----------------
__global__ __launch_bounds__(256) void cvt2_f32_bf16(const float* __restrict__ wg,
                                                     const float* __restrict__ wu,
                                                     unsigned short* __restrict__ og,
                                                     unsigned short* __restrict__ ou) {
    const int NG4 = 5120 * 2048 / 4;
    const int NU4 = 1024 * 2048 / 4;
    int i = blockIdx.x * 256 + threadIdx.x;
    if (i < NG4) {
        float4 v = reinterpret_cast<const float4*>(wg)[i];
        ushort4 o; o.x = f2bf(v.x); o.y = f2bf(v.y); o.z = f2bf(v.z); o.w = f2bf(v.w);
        reinterpret_cast<ushort4*>(og)[i] = o;
    } else if (i < NG4 + NU4) {
        int j = i - NG4;
        float4 v = reinterpret_cast<const float4*>(wu)[j];
        ushort4 o; o.x = f2bf(v.x); o.y = f2bf(v.y); o.z = f2bf(v.z); o.w = f2bf(v.w);
        reinterpret_cast<ushort4*>(ou)[j] = o;
    }
}

// ---------------- LN1: concat(x,h) -> layernorm -> bf16 ----------------
__global__ __launch_bounds__(256) void ln1_kernel(const float* __restrict__ x, const float* __restrict__ h,
                                                  const float* __restrict__ w, const float* __restrict__ b,
                                                  unsigned short* __restrict__ out) {
    const int row = blockIdx.x;
    const int t = threadIdx.x;
    const float4 xv = reinterpret_cast<const float4*>(x + (size_t)row * D_DIM)[t];
    const float4 hv = reinterpret_cast<const float4*>(h + (size_t)row * D_DIM)[t];
    float s  = xv.x + xv.y + xv.z + xv.w + hv.x + hv.y + hv.z + hv.w;
    float s2 = xv.x*xv.x + xv.y*xv.y + xv.z*xv.z + xv.w*xv.w
             + hv.x*hv.x + hv.y*hv.y + hv.z*hv.z + hv.w*hv.w;
#pragma unroll
    for (int off = 32; off > 0; off >>= 1) { s += __shfl_xor(s, off); s2 += __shfl_xor(s2, off); }
    __shared__ float red[8];
    const int wid = t >> 6, lane = t & 63;
    if (lane == 0) { red[wid] = s; red[4 + wid] = s2; }
    __syncthreads();
    s  = red[0] + red[1] + red[2] + red[3];
    s2 = red[4] + red[5] + red[6] + red[7];
    const float mu  = s * (1.0f / K_DIM);
    const float var = s2 * (1.0f / K_DIM) - mu * mu;
    const float inv = rsqrtf(var + 1e-5f);
    const float4 w0 = reinterpret_cast<const float4*>(w)[t];
    const float4 b0 = reinterpret_cast<const float4*>(b)[t];
    const float4 w1 = reinterpret_cast<const float4*>(w + D_DIM)[t];
    const float4 b1 = reinterpret_cast<const float4*>(b + D_DIM)[t];
    ushort4 o0, o1;
    o0.x = f2bf((xv.x - mu) * inv * w0.x + b0.x);
    o0.y = f2bf((xv.y - mu) * inv * w0.y + b0.y);
    o0.z = f2bf((xv.z - mu) * inv * w0.z + b0.z);
    o0.w = f2bf((xv.w - mu) * inv * w0.w + b0.w);
    o1.x = f2bf((hv.x - mu) * inv * w1.x + b1.x);
    o1.y = f2bf((hv.y - mu) * inv * w1.y + b1.y);
    o1.z = f2bf((hv.z - mu) * inv * w1.z + b1.z);
    o1.w = f2bf((hv.w - mu) * inv * w1.w + b1.w);
    reinterpret_cast<ushort4*>(out + (size_t)row * K_DIM)[t] = o0;
    reinterpret_cast<ushort4*>(out + (size_t)row * K_DIM + D_DIM)[t] = o1;
}

// ---------------- gate sigmoid + LN2 -> bf16 inp2 ----------------
__global__ __launch_bounds__(256) void gate_ln2_kernel(const float* __restrict__ x, const float* __restrict__ h,
                                                       const unsigned short* __restrict__ gates,
                                                       const float* __restrict__ w, const float* __restrict__ b,
                                                       unsigned short* __restrict__ out) {
    const int row = blockIdx.x;
    const int t = threadIdx.x;
    const float4 xv = reinterpret_cast<const float4*>(x + (size_t)row * D_DIM)[t];
    const float4 hv = reinterpret_cast<const float4*>(h + (size_t)row * D_DIM)[t];
    const ushort4 g0v = reinterpret_cast<const ushort4*>(gates + (size_t)row * NG)[t];
    const ushort4 g1v = reinterpret_cast<const ushort4*>(gates + (size_t)row * NG + D_DIM)[t];
    float a0 = xv.x * sigm(bf2f(g0v.x));
    float a1 = xv.y * sigm(bf2f(g0v.y));
    float a2 = xv.z * sigm(bf2f(g0v.z));
    float a3 = xv.w * sigm(bf2f(g0v.w));
    float c0 = hv.x * sigm(bf2f(g1v.x));
    float c1 = hv.y * sigm(bf2f(g1v.y));
    float c2 = hv.z * sigm(bf2f(g1v.z));
    float c3 = hv.w * sigm(bf2f(g1v.w));
    float s  = a0 + a1 + a2 + a3 + c0 + c1 + c2 + c3;
    float s2 = a0*a0 + a1*a1 + a2*a2 + a3*a3 + c0*c0 + c1*c1 + c2*c2 + c3*c3;
#pragma unroll
    for (int off = 32; off > 0; off >>= 1) { s += __shfl_xor(s, off); s2 += __shfl_xor(s2, off); }
    __shared__ float red[8];
    const int wid = t >> 6, lane = t & 63;
    if (lane == 0) { red[wid] = s; red[4 + wid] = s2; }
    __syncthreads();
    s  = red[0] + red[1] + red[2] + red[3];
    s2 = red[4] + red[5] + red[6] + red[7];
    const float mu  = s * (1.0f / K_DIM);
    const float var = s2 * (1.0f / K_DIM) - mu * mu;
    const float inv = rsqrtf(var + 1e-5f);
    const float4 w0 = reinterpret_cast<const float4*>(w)[t];
    const float4 b0 = reinterpret_cast<const float4*>(b)[t];
    const float4 w1 = reinterpret_cast<const float4*>(w + D_DIM)[t];
    const float4 b1 = reinterpret_cast<const float4*>(b + D_DIM)[t];
    ushort4 o0, o1;
    o0.x = f2bf((a0 - mu) * inv * w0.x + b0.x);
    o0.y = f2bf((a1 - mu) * inv * w0.y + b0.y);
    o0.z = f2bf((a2 - mu) * inv * w0.z + b0.z);
    o0.w = f2bf((a3 - mu) * inv * w0.w + b0.w);
    o1.x = f2bf((c0 - mu) * inv * w1.x + b1.x);
    o1.y = f2bf((c1 - mu) * inv * w1.y + b1.y);
    o1.z = f2bf((c2 - mu) * inv * w1.z + b1.z);
    o1.w = f2bf((c3 - mu) * inv * w1.w + b1.w);
    reinterpret_cast<ushort4*>(out + (size_t)row * K_DIM)[t] = o0;
    reinterpret_cast<ushort4*>(out + (size_t)row * K_DIM + D_DIM)[t] = o1;
}

// ---------------- GEMM1: 256x256 8-phase pipelined (round-2 race-verified K-loop)
// + LDS-staged coalesced epilogue (new): after final barrier + vmcnt(0), the C-tile
// (256x256 bf16 = 128KB) is staged through the freed smem with a 16B-granular XOR
// swizzle, then streamed out as dwordx4 stores (full 64B lines, ~1.0x write amp). ----
#define PH(BUF, H, KQ, LOADB, STAGE_CODE, VMCNT_CODE) do {                                            \
    bf16x8 aF[4];                                                                                     \
    _Pragma("unroll")                                                                                 \
    for (int m = 0; m < 4; ++m)                                                                       \
        aF[m] = *reinterpret_cast<const bf16x8*>(                                                     \
            &smem[((BUF) * 2 + (H)) * 8192 + ((aRdS[m] ^ ((KQ) * 64)) >> 1)]);                        \
    if (LOADB) {                                                                                      \
        _Pragma("unroll")                                                                             \
        for (int n = 0; n < 4; ++n)                                                                   \
            bF[KQ][n] = *reinterpret_cast<const bf16x8*>(                                             \
                &smem[32768 + ((BUF) * 2 + bHalf) * 8192 + ((bRdS[n] ^ ((KQ) * 64)) >> 1)]);          \
    }                                                                                                 \
    STAGE_CODE;                                                                                       \
    VMCNT_CODE;                                                                                       \
    asm volatile("" ::: "memory");                                                                    \
    __builtin_amdgcn_s_barrier();                                                                     \
    asm volatile("" ::: "memory");                                                                    \
    __builtin_amdgcn_s_setprio(1);                                                                    \
    _Pragma("unroll")                                                                                 \
    for (int m = 0; m < 4; ++m)                                                                       \
        _Pragma("unroll")                                                                             \
        for (int n = 0; n < 4; ++n)                                                                   \
            acc[(H) * 4 + m][n] =                                                                     \
                __builtin_amdgcn_mfma_f32_16x16x32_bf16(aF[m], bF[KQ][n], acc[(H) * 4 + m][n], 0, 0, 0);\
    __builtin_amdgcn_s_setprio(0);                                                                    \
    asm volatile("" ::: "memory");                                                                    \
    __builtin_amdgcn_s_barrier();                                                                     \
    asm volatile("" ::: "memory");                                                                    \
} while (0)

#define VMC4 asm volatile("s_waitcnt vmcnt(4)" ::: "memory")
#define VMC0 asm volatile("s_waitcnt vmcnt(0)" ::: "memory")
#define NOVM (void)0

__global__ __launch_bounds__(512, 2) void gemm_gates8(const unsigned short* __restrict__ A,
                                                      const unsigned short* __restrict__ W,
                                                      const float* __restrict__ bias,
                                                      unsigned short* __restrict__ C) {
    constexpr int K = K_DIM;
    constexpr int NT = K / 64;       // 32 K-tiles
    constexpr int NI = NT / 2;       // 16 iterations
    extern __shared__ unsigned short smem[];   // K-loop: A [0,32768) B [32768,65536); epilogue: C-tile

    const int tid = threadIdx.x;
    const int bid = blockIdx.x;                 // 640 blocks (32 x 20), %8==0
    const int swz = (bid & 7) * 80 + (bid >> 3);
    const int tm = swz / 20;
    const int tn = swz % 20;
    const int Arow0 = tm * 256;
    const int Brow0 = tn * 256;

    const int lane = tid & 63;
    const int wid = tid >> 6;
    const int wr = wid >> 2;        // 0..1 (M)
    const int wc = wid & 3;         // 0..3 (N)
    const int fr = lane & 15;
    const int kb = lane >> 4;
    const int bHalf = wc >> 1;
    const int swzl = (fr & 7) << 4;

    int aRdS[4], bRdS[4];
#pragma unroll
    for (int m = 0; m < 4; ++m)
        aRdS[m] = (((wr * 64 + m * 16 + fr) * 128) + kb * 16) ^ swzl;
#pragma unroll
    for (int n = 0; n < 4; ++n)
        bRdS[n] = ((((wc & 1) * 64 + n * 16 + fr) * 128) + kb * 16) ^ swzl;

    size_t aSrc[2], bSrc[2];
    int ldsDst[2];
#pragma unroll
    for (int l = 0; l < 2; ++l) {
        const int off = (l * 512 + tid) * 16;       // byte off within a 16KB half
        const int r = off >> 7;                     // row 0..127
        const int offS = off ^ ((r & 7) << 4);
        const int cb = (offS & 127) >> 1;           // element col 0..63
        aSrc[l] = (size_t)(Arow0 + r) * K + cb;
        bSrc[l] = (size_t)(Brow0 + r) * K + cb;
        ldsDst[l] = (l * 512 + tid) * 8;            // ushort idx within a half
    }

    auto stageA = [&](int buf, int half, int kt) {
#pragma unroll
        for (int l = 0; l < 2; ++l)
            __builtin_amdgcn_global_load_lds(
                (cg_void*)(A + aSrc[l] + (size_t)half * 128 * K + kt * 64),
                (lds_void*)(&smem[(buf * 2 + half) * 8192 + ldsDst[l]]), 16, 0, 0);
    };
    auto stageB = [&](int buf, int half, int kt) {
#pragma unroll
        for (int l = 0; l < 2; ++l)
            __builtin_amdgcn_global_load_lds(
                (cg_void*)(W + bSrc[l] + (size_t)half * 128 * K + kt * 64),
                (lds_void*)(&smem[32768 + (buf * 2 + half) * 8192 + ldsDst[l]]), 16, 0, 0);
    };

    f32x4 acc[8][4] = {};

    stageA(0, 0, 0); stageA(0, 1, 0); stageB(0, 0, 0); stageB(0, 1, 0);
    stageB(1, 0, 1); stageB(1, 1, 1);
    VMC4;
    asm volatile("" ::: "memory");
    __builtin_amdgcn_s_barrier();
    asm volatile("" ::: "memory");

    for (int i = 0; i < NI; ++i) {
        const int t1 = 2 * i + 1;
        const int t2 = (2 * i + 2) & (NT - 1);
        const int t3 = (2 * i + 3) & (NT - 1);
        bf16x8 bF[2][4];
        PH(0, 0, 0, 1, { stageA(1, 0, t1); stageA(1, 1, t1); }, NOVM);   // P1
        PH(0, 0, 1, 1, ;, NOVM);                                          // P2
        PH(0, 1, 0, 0, { stageA(0, 0, t2); }, NOVM);                      // P3
        PH(0, 1, 1, 0, { stageB(0, 0, t2); }, VMC4);                      // P4
        PH(1, 0, 0, 1, { stageA(0, 1, t2); stageB(0, 1, t2); }, NOVM);    // P5
        PH(1, 0, 1, 1, ;, NOVM);                                          // P6
        PH(1, 1, 0, 0, { stageB(1, 0, t3); }, NOVM);                      // P7
        PH(1, 1, 1, 0, { stageB(1, 1, t3); }, VMC4);                      // P8
    }

    // ---- LDS-staged epilogue ----
    // Drain wrapped in-flight stage loads, then all waves past all LDS reads.
    VMC0;
    asm volatile("" ::: "memory");
    __builtin_amdgcn_s_barrier();
    asm volatile("" ::: "memory");

    // Phase 1: bias + bf16, write C-tile into smem with 16B-granular XOR swizzle.
    // lrow in [0,256), lcol in [0,256); byte = lrow*512 + ((lcol*2) ^ ((lrow&7)<<4)).
#pragma unroll
    for (int n = 0; n < 4; ++n) {
        const int lcol = wc * 64 + n * 16 + fr;
        const float bvv = bias[Brow0 + lcol];
#pragma unroll
        for (int hh = 0; hh < 2; ++hh)
#pragma unroll
            for (int m = 0; m < 4; ++m) {
                const int lr0 = wr * 64 + hh * 128 + m * 16 + kb * 4;
#pragma unroll
                for (int j = 0; j < 4; ++j) {
                    const int lrow = lr0 + j;
                    const int byte = lrow * 512 + ((lcol * 2) ^ ((lrow & 7) << 4));
                    smem[byte >> 1] = f2bf(acc[hh * 4 + m][n][j] + bvv);
                }
            }
    }
    asm volatile("" ::: "memory");
    __builtin_amdgcn_s_barrier();
    asm volatile("" ::: "memory");

    // Phase 2: stream out as dwordx4 (16B) stores, fully coalesced per wave.
#pragma unroll
    for (int k = 0; k < 16; ++k) {
        const int cid = k * 512 + tid;          // 0..8191
        const int row = cid >> 5;               // 0..255
        const int c16 = cid & 31;               // 16B chunk within row
        const int byte = row * 512 + ((c16 * 16) ^ ((row & 7) << 4));
        bf16x8 v = *reinterpret_cast<const bf16x8*>(&smem[byte >> 1]);
        *reinterpret_cast<bf16x8*>(&C[(size_t)(Arow0 + row) * NG + Brow0 + c16 * 8]) = v;
    }
}

// ---------------- GEMM2: 128x128, 3-slot counted-vmcnt pipeline (R5-verified scheme),
// all 512 blocks co-resident (2/CU, capacity 3/CU), fused tanh/softmax/h_new epilogue ----
__global__ __launch_bounds__(256, 3) void gemm_out3(const unsigned short* __restrict__ A,   // inp2 [8192][2048]
                                                    const unsigned short* __restrict__ W,   // Wu [1024][2048]
                                                    const float* __restrict__ bias,         // bu [1024]
                                                    const unsigned short* __restrict__ gates,
                                                    const float* __restrict__ x, const float* __restrict__ h,
                                                    float* __restrict__ out) {
    constexpr int K = K_DIM;
    constexpr int NTK = K / 32;                 // 64 K-tiles
    extern __shared__ unsigned short smem[];    // A: 3 x 4096 ushorts [0,12288); B: [12288,24576)

    const int tid = threadIdx.x;
    const int bid = blockIdx.x;                 // 512 blocks (64 M x 8 N), %8==0
    const int swz = (bid & 7) * 64 + (bid >> 3);
    const int tn = swz & 7;
    const int tm = swz >> 3;
    const int Arow0 = tm * 128;
    const int Brow0 = tn * 128;

    const int lane = tid & 63;
    const int wid = tid >> 6;
    const int wr = wid >> 1;        // 0..1 (M)
    const int wc = wid & 1;         // 0..1 (N)
    const int fr = lane & 15;
    const int kb = lane >> 4;

    int aRd[4], bRd[4];
#pragma unroll
    for (int m = 0; m < 4; ++m) {
        const int row = wr * 64 + m * 16 + fr;
        aRd[m] = ((row >> 1) * 128 + ((((row & 1) * 64) + kb * 16) ^ (((row >> 1) & 7) << 4))) >> 1;
    }
#pragma unroll
    for (int n = 0; n < 4; ++n) {
        const int row = wc * 64 + n * 16 + fr;
        bRd[n] = ((row >> 1) * 128 + ((((row & 1) * 64) + kb * 16) ^ (((row >> 1) & 7) << 4))) >> 1;
    }

    size_t aSrcB[2], bSrcB[2];
#pragma unroll
    for (int l = 0; l < 2; ++l) {
        const int t2 = l * 256 + tid;
        const int line = t2 >> 3;
        const int inB = (t2 & 7) * 16;
        const int inBS = inB ^ ((line & 7) << 4);
        const int row = line * 2 + (inBS >> 6);
        const int col = (inBS & 63) >> 1;
        aSrcB[l] = (size_t)(Arow0 + row) * K + col;
        bSrcB[l] = (size_t)(Brow0 + row) * K + col;
    }

    auto stage = [&](int slot, int kt) {
#pragma unroll
        for (int l = 0; l < 2; ++l)
            __builtin_amdgcn_global_load_lds((cg_void*)(A + aSrcB[l] + kt * 32),
                                             (lds_void*)(&smem[slot * 4096 + (l * 256 + tid) * 8]), 16, 0, 0);
#pragma unroll
        for (int l = 0; l < 2; ++l)
            __builtin_amdgcn_global_load_lds((cg_void*)(W + bSrcB[l] + kt * 32),
                                             (lds_void*)(&smem[12288 + slot * 4096 + (l * 256 + tid) * 8]), 16, 0, 0);
    };

    f32x4 acc[4][4] = {};

    stage(0, 0); stage(1, 1);
    VMC4;
    asm volatile("" ::: "memory");
    __builtin_amdgcn_s_barrier();
    asm volatile("" ::: "memory");

    int sC = 0;
    for (int t = 0; t < NTK; ++t) {
        const int sP = (sC == 0) ? 2 : sC - 1;
        const int kt2 = (t + 2) & (NTK - 1);

        bf16x8 aF[4], bF[4];
#pragma unroll
        for (int m = 0; m < 4; ++m)
            aF[m] = *reinterpret_cast<const bf16x8*>(&smem[sC * 4096 + aRd[m]]);
#pragma unroll
        for (int n = 0; n < 4; ++n)
            bF[n] = *reinterpret_cast<const bf16x8*>(&smem[12288 + sC * 4096 + bRd[n]]);

        stage(sP, kt2);
        VMC4;
        asm volatile("" ::: "memory");
        __builtin_amdgcn_s_barrier();
        asm volatile("" ::: "memory");

        __builtin_amdgcn_s_setprio(1);
#pragma unroll
        for (int m = 0; m < 4; ++m)
#pragma unroll
            for (int n = 0; n < 4; ++n)
                acc[m][n] = __builtin_amdgcn_mfma_f32_16x16x32_bf16(aF[m], bF[n], acc[m][n], 0, 0, 0);
        __builtin_amdgcn_s_setprio(0);
        asm volatile("" ::: "memory");
        __builtin_amdgcn_s_barrier();
        asm volatile("" ::: "memory");

        sC = (sC == 2) ? 0 : sC + 1;
    }

    const int crow0 = Arow0 + wr * 64;
    const int ccol0 = Brow0 + wc * 64;
#pragma unroll
    for (int n = 0; n < 4; ++n) {
        const int c = ccol0 + n * 16 + fr;
        const float bvv = bias[c];
#pragma unroll
        for (int m = 0; m < 4; ++m) {
            const size_t r0 = (size_t)crow0 + m * 16 + kb * 4;
#pragma unroll
            for (int j = 0; j < 4; ++j) {
                const size_t r = r0 + j;
                const float u = tanhf(acc[m][n][j] + bvv);
                const size_t gb = r * NG + c;
                const float g2 = bf2f(gates[gb + 2 * D_DIM]);
                const float g3 = bf2f(gates[gb + 3 * D_DIM]);
                const float g4 = bf2f(gates[gb + 4 * D_DIM]);
                const float mx = fmaxf(fmaxf(g2, g3), g4);
                const float e2 = __expf(g2 - mx), e3 = __expf(g3 - mx), e4 = __expf(g4 - mx);
                const float zi = 1.0f / (e2 + e3 + e4);
                const size_t xi = r * D_DIM + c;
                out[xi] = (x[xi] * e2 + h[xi] * e3 + u * e4) * zi;
            }
        }
    }
}

extern "C" void kernel_launch(void* const* d_in, const int* in_sizes, int n_in,
                              void* d_out, int out_size, void* d_ws, size_t ws_size,
                              hipStream_t stream) {
    const float* x    = (const float*)d_in[0];
    const float* h    = (const float*)d_in[1];
    const float* ln_w = (const float*)d_in[2];
    const float* ln_b = (const float*)d_in[3];
    const float* ln2_w= (const float*)d_in[4];
    const float* ln2_b= (const float*)d_in[5];
    const float* Wg   = (const float*)d_in[6];
    const float* bg   = (const float*)d_in[7];
    const float* Wu   = (const float*)d_in[8];
    const float* bu   = (const float*)d_in[9];
    float* out = (float*)d_out;

    char* ws = (char*)d_ws;
    unsigned short* inp   = (unsigned short*)(ws);                                   // [8192][2048] (reused as inp2)
    unsigned short* Wg_b  = (unsigned short*)(ws + 33554432);                        // [5120][2048]
    unsigned short* Wu_b  = (unsigned short*)(ws + 33554432 + 20971520);             // [1024][2048]
    unsigned short* gates = (unsigned short*)(ws + 33554432 + 20971520 + 4194304);   // [8192][5120]

    (void)hipFuncSetAttribute((const void*)gemm_gates8,
                              hipFuncAttributeMaxDynamicSharedMemorySize, 131072);
    (void)hipFuncSetAttribute((const void*)gemm_out3,
                              hipFuncAttributeMaxDynamicSharedMemorySize, 49152);

    const int nCvt4 = 5120 * 2048 / 4 + 1024 * 2048 / 4;
    cvt2_f32_bf16<<<(nCvt4 + 255) / 256, 256, 0, stream>>>(Wg, Wu, Wg_b, Wu_b);
    ln1_kernel<<<8192, 256, 0, stream>>>(x, h, ln_w, ln_b, inp);
    gemm_gates8<<<640, 512, 131072, stream>>>(inp, Wg_b, bg, gates);
    gate_ln2_kernel<<<8192, 256, 0, stream>>>(x, h, gates, ln2_w, ln2_b, inp);
    gemm_out3<<<512, 256, 49152, stream>>>(inp, Wu_b, bu, gates, x, h, out);
}

// Round 8
// 296.845 us; speedup vs baseline: 1.1728x; 1.0676x over previous
//
#include <hip/hip_runtime.h>

typedef __attribute__((ext_vector_type(8))) __bf16 bf16x8;
typedef __attribute__((ext_vector_type(4))) float f32x4;

#define B_ROWS 8192
#define D_DIM  1024
#define K_DIM  2048
#define NG     5120

typedef const __attribute__((address_space(1))) void cg_void;
typedef __attribute__((address_space(3))) void lds_void;

__device__ __forceinline__ float bf2f(unsigned short u) {
    union { unsigned int ui; float f; } c; c.ui = ((unsigned int)u) << 16; return c.f;
}
__device__ __forceinline__ unsigned short f2bf(float f) {
    unsigned int u = __float_as_uint(f);
    unsigned int r = u + 0x7fffu + ((u >> 16) & 1u);
    return (unsigned short)(r >> 16);
}
__device__ __forceinline__ float sigm(float v) { return 1.0f / (1.0f + __expf(-v)); }

// ---------------- weight f32 -> bf16 convert (both weights, one launch) ----------------
__global__ __launch_bounds__(256) void cvt2_f32_bf16(const float* __restrict__ wg,
                                                     const float* __restrict__ wu,
                                                     unsigned short* __restrict__ og,
                                                     unsigned short* __restrict__ ou) {
    const int NG4 = 5120 * 2048 / 4;
    const int NU4 = 1024 * 2048 / 4;
    int i = blockIdx.x * 256 + threadIdx.x;
    if (i < NG4) {
        float4 v = reinterpret_cast<const float4*>(wg)[i];
        ushort4 o; o.x = f2bf(v.x); o.y = f2bf(v.y); o.z = f2bf(v.z); o.w = f2bf(v.w);
        reinterpret_cast<ushort4*>(og)[i] = o;
    } else if (i < NG4 + NU4) {
        int j = i - NG4;
        float4 v = reinterpret_cast<const float4*>(wu)[j];
        ushort4 o; o.x = f2bf(v.x); o.y = f2bf(v.y); o.z = f2bf(v.z); o.w = f2bf(v.w);
        reinterpret_cast<ushort4*>(ou)[j] = o;
    }
}

// ---------------- LN1: concat(x,h) -> layernorm -> bf16 ----------------
__global__ __launch_bounds__(256) void ln1_kernel(const float* __restrict__ x, const float* __restrict__ h,
                                                  const float* __restrict__ w, const float* __restrict__ b,
                                                  unsigned short* __restrict__ out) {
    const int row = blockIdx.x;
    const int t = threadIdx.x;
    const float4 xv = reinterpret_cast<const float4*>(x + (size_t)row * D_DIM)[t];
    const float4 hv = reinterpret_cast<const float4*>(h + (size_t)row * D_DIM)[t];
    float s  = xv.x + xv.y + xv.z + xv.w + hv.x + hv.y + hv.z + hv.w;
    float s2 = xv.x*xv.x + xv.y*xv.y + xv.z*xv.z + xv.w*xv.w
             + hv.x*hv.x + hv.y*hv.y + hv.z*hv.z + hv.w*hv.w;
#pragma unroll
    for (int off = 32; off > 0; off >>= 1) { s += __shfl_xor(s, off); s2 += __shfl_xor(s2, off); }
    __shared__ float red[8];
    const int wid = t >> 6, lane = t & 63;
    if (lane == 0) { red[wid] = s; red[4 + wid] = s2; }
    __syncthreads();
    s  = red[0] + red[1] + red[2] + red[3];
    s2 = red[4] + red[5] + red[6] + red[7];
    const float mu  = s * (1.0f / K_DIM);
    const float var = s2 * (1.0f / K_DIM) - mu * mu;
    const float inv = rsqrtf(var + 1e-5f);
    const float4 w0 = reinterpret_cast<const float4*>(w)[t];
    const float4 b0 = reinterpret_cast<const float4*>(b)[t];
    const float4 w1 = reinterpret_cast<const float4*>(w + D_DIM)[t];
    const float4 b1 = reinterpret_cast<const float4*>(b + D_DIM)[t];
    ushort4 o0, o1;
    o0.x = f2bf((xv.x - mu) * inv * w0.x + b0.x);
    o0.y = f2bf((xv.y - mu) * inv * w0.y + b0.y);
    o0.z = f2bf((xv.z - mu) * inv * w0.z + b0.z);
    o0.w = f2bf((xv.w - mu) * inv * w0.w + b0.w);
    o1.x = f2bf((hv.x - mu) * inv * w1.x + b1.x);
    o1.y = f2bf((hv.y - mu) * inv * w1.y + b1.y);
    o1.z = f2bf((hv.z - mu) * inv * w1.z + b1.z);
    o1.w = f2bf((hv.w - mu) * inv * w1.w + b1.w);
    reinterpret_cast<ushort4*>(out + (size_t)row * K_DIM)[t] = o0;
    reinterpret_cast<ushort4*>(out + (size_t)row * K_DIM + D_DIM)[t] = o1;
}

// ---------------- gate sigmoid + LN2 -> bf16 inp2 ----------------
__global__ __launch_bounds__(256) void gate_ln2_kernel(const float* __restrict__ x, const float* __restrict__ h,
                                                       const unsigned short* __restrict__ gates,
                                                       const float* __restrict__ w, const float* __restrict__ b,
                                                       unsigned short* __restrict__ out) {
    const int row = blockIdx.x;
    const int t = threadIdx.x;
    const float4 xv = reinterpret_cast<const float4*>(x + (size_t)row * D_DIM)[t];
    const float4 hv = reinterpret_cast<const float4*>(h + (size_t)row * D_DIM)[t];
    const ushort4 g0v = reinterpret_cast<const ushort4*>(gates + (size_t)row * NG)[t];
    const ushort4 g1v = reinterpret_cast<const ushort4*>(gates + (size_t)row * NG + D_DIM)[t];
    float a0 = xv.x * sigm(bf2f(g0v.x));
    float a1 = xv.y * sigm(bf2f(g0v.y));
    float a2 = xv.z * sigm(bf2f(g0v.z));
    float a3 = xv.w * sigm(bf2f(g0v.w));
    float c0 = hv.x * sigm(bf2f(g1v.x));
    float c1 = hv.y * sigm(bf2f(g1v.y));
    float c2 = hv.z * sigm(bf2f(g1v.z));
    float c3 = hv.w * sigm(bf2f(g1v.w));
    float s  = a0 + a1 + a2 + a3 + c0 + c1 + c2 + c3;
    float s2 = a0*a0 + a1*a1 + a2*a2 + a3*a3 + c0*c0 + c1*c1 + c2*c2 + c3*c3;
#pragma unroll
    for (int off = 32; off > 0; off >>= 1) { s += __shfl_xor(s, off); s2 += __shfl_xor(s2, off); }
    __shared__ float red[8];
    const int wid = t >> 6, lane = t & 63;
    if (lane == 0) { red[wid] = s; red[4 + wid] = s2; }
    __syncthreads();
    s  = red[0] + red[1] + red[2] + red[3];
    s2 = red[4] + red[5] + red[6] + red[7];
    const float mu  = s * (1.0f / K_DIM);
    const float var = s2 * (1.0f / K_DIM) - mu * mu;
    const float inv = rsqrtf(var + 1e-5f);
    const float4 w0 = reinterpret_cast<const float4*>(w)[t];
    const float4 b0 = reinterpret_cast<const float4*>(b)[t];
    const float4 w1 = reinterpret_cast<const float4*>(w + D_DIM)[t];
    const float4 b1 = reinterpret_cast<const float4*>(b + D_DIM)[t];
    ushort4 o0, o1;
    o0.x = f2bf((a0 - mu) * inv * w0.x + b0.x);
    o0.y = f2bf((a1 - mu) * inv * w0.y + b0.y);
    o0.z = f2bf((a2 - mu) * inv * w0.z + b0.z);
    o0.w = f2bf((a3 - mu) * inv * w0.w + b0.w);
    o1.x = f2bf((c0 - mu) * inv * w1.x + b1.x);
    o1.y = f2bf((c1 - mu) * inv * w1.y + b1.y);
    o1.z = f2bf((c2 - mu) * inv * w1.z + b1.z);
    o1.w = f2bf((c3 - mu) * inv * w1.w + b1.w);
    reinterpret_cast<ushort4*>(out + (size_t)row * K_DIM)[t] = o0;
    reinterpret_cast<ushort4*>(out + (size_t)row * K_DIM + D_DIM)[t] = o1;
}

// ---------------- GEMM1: uniform-round grid (768 blocks) ----------------
// Blocks 0-511: full 256x256 tiles (tn 0..15), R2 race-verified 8-phase K-loop +
//   R7 LDS-staged epilogue (both byte-identical).
// Blocks 512-767: half tiles 128x256 (the tn 16..19 tiles split in M), mirrored
//   8-phase loop with 2 m-frags; ledger: VMC3@P4, VMC4@P8 (re-derived).
// Dispatch order => round1+2 = uniform full blocks, round3 = uniform half blocks.
#define PH(BUF, H, KQ, LOADB, STAGE_CODE, VMCNT_CODE) do {                                            \
    bf16x8 aF[4];                                                                                     \
    _Pragma("unroll")                                                                                 \
    for (int m = 0; m < 4; ++m)                                                                       \
        aF[m] = *reinterpret_cast<const bf16x8*>(                                                     \
            &smem[((BUF) * 2 + (H)) * 8192 + ((aRdS[m] ^ ((KQ) * 64)) >> 1)]);                        \
    if (LOADB) {                                                                                      \
        _Pragma("unroll")                                                                             \
        for (int n = 0; n < 4; ++n)                                                                   \
            bF[KQ][n] = *reinterpret_cast<const bf16x8*>(                                             \
                &smem[32768 + ((BUF) * 2 + bHalf) * 8192 + ((bRdS[n] ^ ((KQ) * 64)) >> 1)]);          \
    }                                                                                                 \
    STAGE_CODE;                                                                                       \
    VMCNT_CODE;                                                                                       \
    asm volatile("" ::: "memory");                                                                    \
    __builtin_amdgcn_s_barrier();                                                                     \
    asm volatile("" ::: "memory");                                                                    \
    __builtin_amdgcn_s_setprio(1);                                                                    \
    _Pragma("unroll")                                                                                 \
    for (int m = 0; m < 4; ++m)                                                                       \
        _Pragma("unroll")                                                                             \
        for (int n = 0; n < 4; ++n)                                                                   \
            acc[(H) * 4 + m][n] =                                                                     \
                __builtin_amdgcn_mfma_f32_16x16x32_bf16(aF[m], bF[KQ][n], acc[(H) * 4 + m][n], 0, 0, 0);\
    __builtin_amdgcn_s_setprio(0);                                                                    \
    asm volatile("" ::: "memory");                                                                    \
    __builtin_amdgcn_s_barrier();                                                                     \
    asm volatile("" ::: "memory");                                                                    \
} while (0)

// half-tile phase: 2 m-frags, 8 MFMA
#define PHH(BUF, H, KQ, LOADB, STAGE_CODE, VMCNT_CODE) do {                                           \
    bf16x8 aFh[2];                                                                                    \
    _Pragma("unroll")                                                                                 \
    for (int m = 0; m < 2; ++m)                                                                       \
        aFh[m] = *reinterpret_cast<const bf16x8*>(                                                    \
            &smem[((BUF) * 2 + (H)) * 8192 + ((aRdH[m] ^ ((KQ) * 64)) >> 1)]);                        \
    if (LOADB) {                                                                                      \
        _Pragma("unroll")                                                                             \
        for (int n = 0; n < 4; ++n)                                                                   \
            bF[KQ][n] = *reinterpret_cast<const bf16x8*>(                                             \
                &smem[32768 + ((BUF) * 2 + bHalf) * 8192 + ((bRdS[n] ^ ((KQ) * 64)) >> 1)]);          \
    }                                                                                                 \
    STAGE_CODE;                                                                                       \
    VMCNT_CODE;                                                                                      \
    asm volatile("" ::: "memory");                                                                    \
    __builtin_amdgcn_s_barrier();                                                                     \
    asm volatile("" ::: "memory");                                                                    \
    __builtin_amdgcn_s_setprio(1);                                                                    \
    _Pragma("unroll")                                                                                 \
    for (int m = 0; m < 2; ++m)                                                                       \
        _Pragma("unroll")                                                                             \
        for (int n = 0; n < 4; ++n)                                                                   \
            acch[(H) * 2 + m][n] =                                                                    \
                __builtin_amdgcn_mfma_f32_16x16x32_bf16(aFh[m], bF[KQ][n], acch[(H) * 2 + m][n], 0, 0, 0);\
    __builtin_amdgcn_s_setprio(0);                                                                    \
    asm volatile("" ::: "memory");                                                                    \
    __builtin_amdgcn_s_barrier();                                                                     \
    asm volatile("" ::: "memory");                                                                    \
} while (0)

#define VMC4 asm volatile("s_waitcnt vmcnt(4)" ::: "memory")
#define VMC3 asm volatile("s_waitcnt vmcnt(3)" ::: "memory")
#define VMC0 asm volatile("s_waitcnt vmcnt(0)" ::: "memory")
#define NOVM (void)0

__global__ __launch_bounds__(512, 2) void gemm_gates8(const unsigned short* __restrict__ A,
                                                      const unsigned short* __restrict__ W,
                                                      const float* __restrict__ bias,
                                                      unsigned short* __restrict__ C) {
    constexpr int K = K_DIM;
    constexpr int NT = K / 64;       // 32 K-tiles
    constexpr int NI = NT / 2;       // 16 iterations
    extern __shared__ unsigned short smem[];

    const int tid = threadIdx.x;
    const int bid = blockIdx.x;                 // 768 blocks: 512 full + 256 half
    const int lane = tid & 63;
    const int wid = tid >> 6;
    const int wr = wid >> 2;        // 0..1 (M)
    const int wc = wid & 3;         // 0..3 (N)
    const int fr = lane & 15;
    const int kb = lane >> 4;
    const int bHalf = wc >> 1;
    const int swzl = (fr & 7) << 4;

    if (bid < 512) {
        // ================= FULL 256x256 tile (R2 core + R7 epilogue) =================
        const int swz = (bid & 7) * 64 + (bid >> 3);
        const int tm = swz >> 4;                 // 0..31
        const int tn = swz & 15;                 // 0..15
        const int Arow0 = tm * 256;
        const int Brow0 = tn * 256;

        int aRdS[4], bRdS[4];
#pragma unroll
        for (int m = 0; m < 4; ++m)
            aRdS[m] = (((wr * 64 + m * 16 + fr) * 128) + kb * 16) ^ swzl;
#pragma unroll
        for (int n = 0; n < 4; ++n)
            bRdS[n] = ((((wc & 1) * 64 + n * 16 + fr) * 128) + kb * 16) ^ swzl;

        size_t aSrc[2], bSrc[2];
        int ldsDst[2];
#pragma unroll
        for (int l = 0; l < 2; ++l) {
            const int off = (l * 512 + tid) * 16;
            const int r = off >> 7;
            const int offS = off ^ ((r & 7) << 4);
            const int cb = (offS & 127) >> 1;
            aSrc[l] = (size_t)(Arow0 + r) * K + cb;
            bSrc[l] = (size_t)(Brow0 + r) * K + cb;
            ldsDst[l] = (l * 512 + tid) * 8;
        }

        auto stageA = [&](int buf, int half, int kt) {
#pragma unroll
            for (int l = 0; l < 2; ++l)
                __builtin_amdgcn_global_load_lds(
                    (cg_void*)(A + aSrc[l] + (size_t)half * 128 * K + kt * 64),
                    (lds_void*)(&smem[(buf * 2 + half) * 8192 + ldsDst[l]]), 16, 0, 0);
        };
        auto stageB = [&](int buf, int half, int kt) {
#pragma unroll
            for (int l = 0; l < 2; ++l)
                __builtin_amdgcn_global_load_lds(
                    (cg_void*)(W + bSrc[l] + (size_t)half * 128 * K + kt * 64),
                    (lds_void*)(&smem[32768 + (buf * 2 + half) * 8192 + ldsDst[l]]), 16, 0, 0);
        };

        f32x4 acc[8][4] = {};

        stageA(0, 0, 0); stageA(0, 1, 0); stageB(0, 0, 0); stageB(0, 1, 0);
        stageB(1, 0, 1); stageB(1, 1, 1);
        VMC4;
        asm volatile("" ::: "memory");
        __builtin_amdgcn_s_barrier();
        asm volatile("" ::: "memory");

        for (int i = 0; i < NI; ++i) {
            const int t1 = 2 * i + 1;
            const int t2 = (2 * i + 2) & (NT - 1);
            const int t3 = (2 * i + 3) & (NT - 1);
            bf16x8 bF[2][4];
            PH(0, 0, 0, 1, { stageA(1, 0, t1); stageA(1, 1, t1); }, NOVM);   // P1
            PH(0, 0, 1, 1, ;, NOVM);                                          // P2
            PH(0, 1, 0, 0, { stageA(0, 0, t2); }, NOVM);                      // P3
            PH(0, 1, 1, 0, { stageB(0, 0, t2); }, VMC4);                      // P4
            PH(1, 0, 0, 1, { stageA(0, 1, t2); stageB(0, 1, t2); }, NOVM);    // P5
            PH(1, 0, 1, 1, ;, NOVM);                                          // P6
            PH(1, 1, 0, 0, { stageB(1, 0, t3); }, NOVM);                      // P7
            PH(1, 1, 1, 0, { stageB(1, 1, t3); }, VMC4);                      // P8
        }

        VMC0;
        asm volatile("" ::: "memory");
        __builtin_amdgcn_s_barrier();
        asm volatile("" ::: "memory");

        // LDS-staged epilogue (R7): bias + bf16 into swizzled smem, then dwordx4 stream.
#pragma unroll
        for (int n = 0; n < 4; ++n) {
            const int lcol = wc * 64 + n * 16 + fr;
            const float bvv = bias[Brow0 + lcol];
#pragma unroll
            for (int hh = 0; hh < 2; ++hh)
#pragma unroll
                for (int m = 0; m < 4; ++m) {
                    const int lr0 = wr * 64 + hh * 128 + m * 16 + kb * 4;
#pragma unroll
                    for (int j = 0; j < 4; ++j) {
                        const int lrow = lr0 + j;
                        const int byte = lrow * 512 + ((lcol * 2) ^ ((lrow & 7) << 4));
                        smem[byte >> 1] = f2bf(acc[hh * 4 + m][n][j] + bvv);
                    }
                }
        }
        asm volatile("" ::: "memory");
        __builtin_amdgcn_s_barrier();
        asm volatile("" ::: "memory");
#pragma unroll
        for (int k = 0; k < 16; ++k) {
            const int cid = k * 512 + tid;
            const int row = cid >> 5;
            const int c16 = cid & 31;
            const int byte = row * 512 + ((c16 * 16) ^ ((row & 7) << 4));
            bf16x8 v = *reinterpret_cast<const bf16x8*>(&smem[byte >> 1]);
            *reinterpret_cast<bf16x8*>(&C[(size_t)(Arow0 + row) * NG + Brow0 + c16 * 8]) = v;
        }
    } else {
        // ================= HALF 128x256 tile (tn 16..19, M-split) =================
        const int idx = bid - 512;                   // 0..255
        const int sidx = (idx & 7) * 32 + (idx >> 3);
        const int t2i = sidx >> 1;                   // 0..127
        const int mhalf = sidx & 1;
        const int tm = t2i >> 2;                     // 0..31
        const int tn = 16 + (t2i & 3);               // 16..19
        const int Arow0 = tm * 256 + mhalf * 128;
        const int Brow0 = tn * 256;

        int aRdH[2], bRdS[4];
#pragma unroll
        for (int m = 0; m < 2; ++m)
            aRdH[m] = (((wr * 32 + m * 16 + fr) * 128) + kb * 16) ^ swzl;
#pragma unroll
        for (int n = 0; n < 4; ++n)
            bRdS[n] = ((((wc & 1) * 64 + n * 16 + fr) * 128) + kb * 16) ^ swzl;

        // A half = 64 rows x 64 k = 8KB = 1 load/thread; B as in full (2 loads/half)
        size_t aSrcH;
        {
            const int off = tid * 16;
            const int r = off >> 7;                  // 0..63
            const int offS = off ^ ((r & 7) << 4);
            const int cb = (offS & 127) >> 1;
            aSrcH = (size_t)(Arow0 + r) * K + cb;
        }
        size_t bSrc[2];
        int ldsDst[2];
#pragma unroll
        for (int l = 0; l < 2; ++l) {
            const int off = (l * 512 + tid) * 16;
            const int r = off >> 7;
            const int offS = off ^ ((r & 7) << 4);
            const int cb = (offS & 127) >> 1;
            bSrc[l] = (size_t)(Brow0 + r) * K + cb;
            ldsDst[l] = (l * 512 + tid) * 8;
        }

        auto stageAH = [&](int buf, int half, int kt) {
            __builtin_amdgcn_global_load_lds(
                (cg_void*)(A + aSrcH + (size_t)half * 64 * K + kt * 64),
                (lds_void*)(&smem[(buf * 2 + half) * 8192 + tid * 8]), 16, 0, 0);
        };
        auto stageB = [&](int buf, int half, int kt) {
#pragma unroll
            for (int l = 0; l < 2; ++l)
                __builtin_amdgcn_global_load_lds(
                    (cg_void*)(W + bSrc[l] + (size_t)half * 128 * K + kt * 64),
                    (lds_void*)(&smem[32768 + (buf * 2 + half) * 8192 + ldsDst[l]]), 16, 0, 0);
        };

        f32x4 acch[4][4] = {};

        // prologue: t0 full (A 2 + B 4 = 6 loads) + t1's B (4) -> 10; confirm t0 via vmcnt(4)
        stageAH(0, 0, 0); stageAH(0, 1, 0); stageB(0, 0, 0); stageB(0, 1, 0);
        stageB(1, 0, 1); stageB(1, 1, 1);
        VMC4;
        asm volatile("" ::: "memory");
        __builtin_amdgcn_s_barrier();
        asm volatile("" ::: "memory");

        for (int i = 0; i < NI; ++i) {
            const int t1 = 2 * i + 1;
            const int t2 = (2 * i + 2) & (NT - 1);
            const int t3 = (2 * i + 3) & (NT - 1);
            bf16x8 bF[2][4];
            PHH(0, 0, 0, 1, { stageAH(1, 0, t1); stageAH(1, 1, t1); }, NOVM);   // P1 +2
            PHH(0, 0, 1, 1, ;, NOVM);                                            // P2
            PHH(0, 1, 0, 0, { stageAH(0, 0, t2); }, NOVM);                       // P3 +1
            PHH(0, 1, 1, 0, { stageB(0, 0, t2); }, VMC3);                        // P4 +2, confirm t1 (6)
            PHH(1, 0, 0, 1, { stageAH(0, 1, t2); stageB(0, 1, t2); }, NOVM);     // P5 +3
            PHH(1, 0, 1, 1, ;, NOVM);                                            // P6
            PHH(1, 1, 0, 0, { stageB(1, 0, t3); }, NOVM);                        // P7 +2
            PHH(1, 1, 1, 0, { stageB(1, 1, t3); }, VMC4);                        // P8 +2, confirm t2 (6)
        }

        VMC0;
        asm volatile("" ::: "memory");
        __builtin_amdgcn_s_barrier();
        asm volatile("" ::: "memory");

        // LDS-staged epilogue, 128-row tile (64KB)
#pragma unroll
        for (int n = 0; n < 4; ++n) {
            const int lcol = wc * 64 + n * 16 + fr;
            const float bvv = bias[Brow0 + lcol];
#pragma unroll
            for (int hh = 0; hh < 2; ++hh)
#pragma unroll
                for (int m = 0; m < 2; ++m) {
                    const int lr0 = hh * 64 + wr * 32 + m * 16 + kb * 4;
#pragma unroll
                    for (int j = 0; j < 4; ++j) {
                        const int lrow = lr0 + j;
                        const int byte = lrow * 512 + ((lcol * 2) ^ ((lrow & 7) << 4));
                        smem[byte >> 1] = f2bf(acch[hh * 2 + m][n][j] + bvv);
                    }
                }
        }
        asm volatile("" ::: "memory");
        __builtin_amdgcn_s_barrier();
        asm volatile("" ::: "memory");
#pragma unroll
        for (int k = 0; k < 8; ++k) {
            const int cid = k * 512 + tid;
            const int row = cid >> 5;               // 0..127
            const int c16 = cid & 31;
            const int byte = row * 512 + ((c16 * 16) ^ ((row & 7) << 4));
            bf16x8 v = *reinterpret_cast<const bf16x8*>(&smem[byte >> 1]);
            *reinterpret_cast<bf16x8*>(&C[(size_t)(Arow0 + row) * NG + Brow0 + c16 * 8]) = v;
        }
    }
}

// ---------------- GEMM2: 128x128, 3-slot counted-vmcnt pipeline (R5-verified scheme)
// + LDS-staged f32 epilogue (new this round): combine result staged in smem (bank-
// swizzled), streamed as float4 -> full-line out writes. ----
__global__ __launch_bounds__(256, 3) void gemm_out3(const unsigned short* __restrict__ A,   // inp2 [8192][2048]
                                                    const unsigned short* __restrict__ W,   // Wu [1024][2048]
                                                    const float* __restrict__ bias,         // bu [1024]
                                                    const unsigned short* __restrict__ gates,
                                                    const float* __restrict__ x, const float* __restrict__ h,
                                                    float* __restrict__ out) {
    constexpr int K = K_DIM;
    constexpr int NTK = K / 32;                 // 64 K-tiles
    extern __shared__ unsigned short smem[];    // K-loop: A 3x4096 us [0,12288), B [12288,24576); epilogue: f32 tile

    const int tid = threadIdx.x;
    const int bid = blockIdx.x;                 // 512 blocks (64 M x 8 N), %8==0
    const int swz = (bid & 7) * 64 + (bid >> 3);
    const int tn = swz & 7;
    const int tm = swz >> 3;
    const int Arow0 = tm * 128;
    const int Brow0 = tn * 128;

    const int lane = tid & 63;
    const int wid = tid >> 6;
    const int wr = wid >> 1;        // 0..1 (M)
    const int wc = wid & 1;         // 0..1 (N)
    const int fr = lane & 15;
    const int kb = lane >> 4;

    int aRd[4], bRd[4];
#pragma unroll
    for (int m = 0; m < 4; ++m) {
        const int row = wr * 64 + m * 16 + fr;
        aRd[m] = ((row >> 1) * 128 + ((((row & 1) * 64) + kb * 16) ^ (((row >> 1) & 7) << 4))) >> 1;
    }
#pragma unroll
    for (int n = 0; n < 4; ++n) {
        const int row = wc * 64 + n * 16 + fr;
        bRd[n] = ((row >> 1) * 128 + ((((row & 1) * 64) + kb * 16) ^ (((row >> 1) & 7) << 4))) >> 1;
    }

    size_t aSrcB[2], bSrcB[2];
#pragma unroll
    for (int l = 0; l < 2; ++l) {
        const int t2 = l * 256 + tid;
        const int line = t2 >> 3;
        const int inB = (t2 & 7) * 16;
        const int inBS = inB ^ ((line & 7) << 4);
        const int row = line * 2 + (inBS >> 6);
        const int col = (inBS & 63) >> 1;
        aSrcB[l] = (size_t)(Arow0 + row) * K + col;
        bSrcB[l] = (size_t)(Brow0 + row) * K + col;
    }

    auto stage = [&](int slot, int kt) {
#pragma unroll
        for (int l = 0; l < 2; ++l)
            __builtin_amdgcn_global_load_lds((cg_void*)(A + aSrcB[l] + kt * 32),
                                             (lds_void*)(&smem[slot * 4096 + (l * 256 + tid) * 8]), 16, 0, 0);
#pragma unroll
        for (int l = 0; l < 2; ++l)
            __builtin_amdgcn_global_load_lds((cg_void*)(W + bSrcB[l] + kt * 32),
                                             (lds_void*)(&smem[12288 + slot * 4096 + (l * 256 + tid) * 8]), 16, 0, 0);
    };

    f32x4 acc[4][4] = {};

    stage(0, 0); stage(1, 1);
    VMC4;
    asm volatile("" ::: "memory");
    __builtin_amdgcn_s_barrier();
    asm volatile("" ::: "memory");

    int sC = 0;
    for (int t = 0; t < NTK; ++t) {
        const int sP = (sC == 0) ? 2 : sC - 1;
        const int kt2 = (t + 2) & (NTK - 1);

        bf16x8 aF[4], bF[4];
#pragma unroll
        for (int m = 0; m < 4; ++m)
            aF[m] = *reinterpret_cast<const bf16x8*>(&smem[sC * 4096 + aRd[m]]);
#pragma unroll
        for (int n = 0; n < 4; ++n)
            bF[n] = *reinterpret_cast<const bf16x8*>(&smem[12288 + sC * 4096 + bRd[n]]);

        stage(sP, kt2);
        VMC4;
        asm volatile("" ::: "memory");
        __builtin_amdgcn_s_barrier();
        asm volatile("" ::: "memory");

        __builtin_amdgcn_s_setprio(1);
#pragma unroll
        for (int m = 0; m < 4; ++m)
#pragma unroll
            for (int n = 0; n < 4; ++n)
                acc[m][n] = __builtin_amdgcn_mfma_f32_16x16x32_bf16(aF[m], bF[n], acc[m][n], 0, 0, 0);
        __builtin_amdgcn_s_setprio(0);
        asm volatile("" ::: "memory");
        __builtin_amdgcn_s_barrier();
        asm volatile("" ::: "memory");

        sC = (sC == 2) ? 0 : sC + 1;
    }

    // drain wrapped in-flight stage loads before smem reuse
    VMC0;
    asm volatile("" ::: "memory");
    __builtin_amdgcn_s_barrier();
    asm volatile("" ::: "memory");

    // fused epilogue: u=tanh(acc+bu); z=softmax(g2,g3,g4); combine -> smem f32 (swizzled)
    float* fsm = reinterpret_cast<float*>(smem);
#pragma unroll
    for (int n = 0; n < 4; ++n) {
        const int lcol = wc * 64 + n * 16 + fr;
        const int c = Brow0 + lcol;
        const float bvv = bias[c];
#pragma unroll
        for (int m = 0; m < 4; ++m) {
            const int lr0 = wr * 64 + m * 16 + kb * 4;
#pragma unroll
            for (int j = 0; j < 4; ++j) {
                const int lrow = lr0 + j;
                const size_t r = (size_t)Arow0 + lrow;
                const float u = tanhf(acc[m][n][j] + bvv);
                const size_t gb = r * NG + c;
                const float g2 = bf2f(gates[gb + 2 * D_DIM]);
                const float g3 = bf2f(gates[gb + 3 * D_DIM]);
                const float g4 = bf2f(gates[gb + 4 * D_DIM]);
                const float mx = fmaxf(fmaxf(g2, g3), g4);
                const float e2 = __expf(g2 - mx), e3 = __expf(g3 - mx), e4 = __expf(g4 - mx);
                const float zi = 1.0f / (e2 + e3 + e4);
                const size_t xi = r * D_DIM + c;
                const float ov = (x[xi] * e2 + h[xi] * e3 + u * e4) * zi;
                const int dw = lrow * 128 + (lcol ^ (((lrow >> 2) & 1) << 4));
                fsm[dw] = ov;
            }
        }
    }
    asm volatile("" ::: "memory");
    __builtin_amdgcn_s_barrier();
    asm volatile("" ::: "memory");

    // stream out as float4, fully coalesced
#pragma unroll
    for (int k = 0; k < 16; ++k) {
        const int cid = k * 256 + tid;          // 0..4095
        const int row = cid >> 5;               // 0..127
        const int c4 = cid & 31;                // float4 chunk
        const int dw = row * 128 + ((c4 * 4) ^ (((row >> 2) & 1) << 4));
        float4 v = *reinterpret_cast<const float4*>(&fsm[dw]);
        *reinterpret_cast<float4*>(&out[(size_t)(Arow0 + row) * D_DIM + Brow0 + c4 * 4]) = v;
    }
}

extern "C" void kernel_launch(void* const* d_in, const int* in_sizes, int n_in,
                              void* d_out, int out_size, void* d_ws, size_t ws_size,
                              hipStream_t stream) {
    const float* x    = (const float*)d_in[0];
    const float* h    = (const float*)d_in[1];
    const float* ln_w = (const float*)d_in[2];
    const float* ln_b = (const float*)d_in[3];
    const float* ln2_w= (const float*)d_in[4];
    const float* ln2_b= (const float*)d_in[5];
    const float* Wg   = (const float*)d_in[6];
    const float* bg   = (const float*)d_in[7];
    const float* Wu   = (const float*)d_in[8];
    const float* bu   = (const float*)d_in[9];
    float* out = (float*)d_out;

    char* ws = (char*)d_ws;
    unsigned short* inp   = (unsigned short*)(ws);                                   // [8192][2048] (reused as inp2)
    unsigned short* Wg_b  = (unsigned short*)(ws + 33554432);                        // [5120][2048]
    unsigned short* Wu_b  = (unsigned short*)(ws + 33554432 + 20971520);             // [1024][2048]
    unsigned short* gates = (unsigned short*)(ws + 33554432 + 20971520 + 4194304);   // [8192][5120]

    (void)hipFuncSetAttribute((const void*)gemm_gates8,
                              hipFuncAttributeMaxDynamicSharedMemorySize, 131072);
    (void)hipFuncSetAttribute((const void*)gemm_out3,
                              hipFuncAttributeMaxDynamicSharedMemorySize, 65536);

    const int nCvt4 = 5120 * 2048 / 4 + 1024 * 2048 / 4;
    cvt2_f32_bf16<<<(nCvt4 + 255) / 256, 256, 0, stream>>>(Wg, Wu, Wg_b, Wu_b);
    ln1_kernel<<<8192, 256, 0, stream>>>(x, h, ln_w, ln_b, inp);
    gemm_gates8<<<768, 512, 131072, stream>>>(inp, Wg_b, bg, gates);
    gate_ln2_kernel<<<8192, 256, 0, stream>>>(x, h, gates, ln2_w, ln2_b, inp);
    gemm_out3<<<512, 256, 65536, stream>>>(inp, Wu_b, bu, gates, x, h, out);
}

// Round 9
// 295.590 us; speedup vs baseline: 1.1778x; 1.0042x over previous
//
#include <hip/hip_runtime.h>

typedef __attribute__((ext_vector_type(8))) __bf16 bf16x8;
typedef __attribute__((ext_vector_type(4))) float f32x4;

#define B_ROWS 8192
#define D_DIM  1024
#define K_DIM  2048
#define NG     5120

typedef const __attribute__((address_space(1))) void cg_void;
typedef __attribute__((address_space(3))) void lds_void;

__device__ __forceinline__ float bf2f(unsigned short u) {
    union { unsigned int ui; float f; } c; c.ui = ((unsigned int)u) << 16; return c.f;
}
__device__ __forceinline__ unsigned short f2bf(float f) {
    unsigned int u = __float_as_uint(f);
    unsigned int r = u + 0x7fffu + ((u >> 16) & 1u);
    return (unsigned short)(r >> 16);
}
__device__ __forceinline__ float sigm(float v) { return 1.0f / (1.0f + __expf(-v)); }

// ---------------- prep: LN1 (blocks 0..8191) + weight cvt (blocks 8192..20479) ----------------
__global__ __launch_bounds__(256) void prep_kernel(const float* __restrict__ x, const float* __restrict__ h,
                                                   const float* __restrict__ w, const float* __restrict__ b,
                                                   unsigned short* __restrict__ outln,
                                                   const float* __restrict__ wg, const float* __restrict__ wu,
                                                   unsigned short* __restrict__ og, unsigned short* __restrict__ ou) {
    const int bid = blockIdx.x;
    const int t = threadIdx.x;
    if (bid < 8192) {
        const int row = bid;
        const float4 xv = reinterpret_cast<const float4*>(x + (size_t)row * D_DIM)[t];
        const float4 hv = reinterpret_cast<const float4*>(h + (size_t)row * D_DIM)[t];
        float s  = xv.x + xv.y + xv.z + xv.w + hv.x + hv.y + hv.z + hv.w;
        float s2 = xv.x*xv.x + xv.y*xv.y + xv.z*xv.z + xv.w*xv.w
                 + hv.x*hv.x + hv.y*hv.y + hv.z*hv.z + hv.w*hv.w;
#pragma unroll
        for (int off = 32; off > 0; off >>= 1) { s += __shfl_xor(s, off); s2 += __shfl_xor(s2, off); }
        __shared__ float red[8];
        const int wid = t >> 6, lane = t & 63;
        if (lane == 0) { red[wid] = s; red[4 + wid] = s2; }
        __syncthreads();
        s  = red[0] + red[1] + red[2] + red[3];
        s2 = red[4] + red[5] + red[6] + red[7];
        const float mu  = s * (1.0f / K_DIM);
        const float var = s2 * (1.0f / K_DIM) - mu * mu;
        const float inv = rsqrtf(var + 1e-5f);
        const float4 w0 = reinterpret_cast<const float4*>(w)[t];
        const float4 b0 = reinterpret_cast<const float4*>(b)[t];
        const float4 w1 = reinterpret_cast<const float4*>(w + D_DIM)[t];
        const float4 b1 = reinterpret_cast<const float4*>(b + D_DIM)[t];
        ushort4 o0, o1;
        o0.x = f2bf((xv.x - mu) * inv * w0.x + b0.x);
        o0.y = f2bf((xv.y - mu) * inv * w0.y + b0.y);
        o0.z = f2bf((xv.z - mu) * inv * w0.z + b0.z);
        o0.w = f2bf((xv.w - mu) * inv * w0.w + b0.w);
        o1.x = f2bf((hv.x - mu) * inv * w1.x + b1.x);
        o1.y = f2bf((hv.y - mu) * inv * w1.y + b1.y);
        o1.z = f2bf((hv.z - mu) * inv * w1.z + b1.z);
        o1.w = f2bf((hv.w - mu) * inv * w1.w + b1.w);
        reinterpret_cast<ushort4*>(outln + (size_t)row * K_DIM)[t] = o0;
        reinterpret_cast<ushort4*>(outln + (size_t)row * K_DIM + D_DIM)[t] = o1;
    } else {
        const int NG4 = 5120 * 2048 / 4;
        const int NU4 = 1024 * 2048 / 4;
        const int i = (bid - 8192) * 256 + t;
        if (i < NG4) {
            float4 v = reinterpret_cast<const float4*>(wg)[i];
            ushort4 o; o.x = f2bf(v.x); o.y = f2bf(v.y); o.z = f2bf(v.z); o.w = f2bf(v.w);
            reinterpret_cast<ushort4*>(og)[i] = o;
        } else if (i < NG4 + NU4) {
            int j = i - NG4;
            float4 v = reinterpret_cast<const float4*>(wu)[j];
            ushort4 o; o.x = f2bf(v.x); o.y = f2bf(v.y); o.z = f2bf(v.z); o.w = f2bf(v.w);
            reinterpret_cast<ushort4*>(ou)[j] = o;
        }
    }
}

// ---------------- gate sigmoid + LN2 -> bf16 inp2 ----------------
__global__ __launch_bounds__(256) void gate_ln2_kernel(const float* __restrict__ x, const float* __restrict__ h,
                                                       const unsigned short* __restrict__ gates,
                                                       const float* __restrict__ w, const float* __restrict__ b,
                                                       unsigned short* __restrict__ out) {
    const int row = blockIdx.x;
    const int t = threadIdx.x;
    const float4 xv = reinterpret_cast<const float4*>(x + (size_t)row * D_DIM)[t];
    const float4 hv = reinterpret_cast<const float4*>(h + (size_t)row * D_DIM)[t];
    const ushort4 g0v = reinterpret_cast<const ushort4*>(gates + (size_t)row * NG)[t];
    const ushort4 g1v = reinterpret_cast<const ushort4*>(gates + (size_t)row * NG + D_DIM)[t];
    float a0 = xv.x * sigm(bf2f(g0v.x));
    float a1 = xv.y * sigm(bf2f(g0v.y));
    float a2 = xv.z * sigm(bf2f(g0v.z));
    float a3 = xv.w * sigm(bf2f(g0v.w));
    float c0 = hv.x * sigm(bf2f(g1v.x));
    float c1 = hv.y * sigm(bf2f(g1v.y));
    float c2 = hv.z * sigm(bf2f(g1v.z));
    float c3 = hv.w * sigm(bf2f(g1v.w));
    float s  = a0 + a1 + a2 + a3 + c0 + c1 + c2 + c3;
    float s2 = a0*a0 + a1*a1 + a2*a2 + a3*a3 + c0*c0 + c1*c1 + c2*c2 + c3*c3;
#pragma unroll
    for (int off = 32; off > 0; off >>= 1) { s += __shfl_xor(s, off); s2 += __shfl_xor(s2, off); }
    __shared__ float red[8];
    const int wid = t >> 6, lane = t & 63;
    if (lane == 0) { red[wid] = s; red[4 + wid] = s2; }
    __syncthreads();
    s  = red[0] + red[1] + red[2] + red[3];
    s2 = red[4] + red[5] + red[6] + red[7];
    const float mu  = s * (1.0f / K_DIM);
    const float var = s2 * (1.0f / K_DIM) - mu * mu;
    const float inv = rsqrtf(var + 1e-5f);
    const float4 w0 = reinterpret_cast<const float4*>(w)[t];
    const float4 b0 = reinterpret_cast<const float4*>(b)[t];
    const float4 w1 = reinterpret_cast<const float4*>(w + D_DIM)[t];
    const float4 b1 = reinterpret_cast<const float4*>(b + D_DIM)[t];
    ushort4 o0, o1;
    o0.x = f2bf((a0 - mu) * inv * w0.x + b0.x);
    o0.y = f2bf((a1 - mu) * inv * w0.y + b0.y);
    o0.z = f2bf((a2 - mu) * inv * w0.z + b0.z);
    o0.w = f2bf((a3 - mu) * inv * w0.w + b0.w);
    o1.x = f2bf((c0 - mu) * inv * w1.x + b1.x);
    o1.y = f2bf((c1 - mu) * inv * w1.y + b1.y);
    o1.z = f2bf((c2 - mu) * inv * w1.z + b1.z);
    o1.w = f2bf((c3 - mu) * inv * w1.w + b1.w);
    reinterpret_cast<ushort4*>(out + (size_t)row * K_DIM)[t] = o0;
    reinterpret_cast<ushort4*>(out + (size_t)row * K_DIM + D_DIM)[t] = o1;
}

// ---------------- GEMM1: uniform-round grid (768 blocks), R8-verified ----------------
#define PH(BUF, H, KQ, LOADB, STAGE_CODE, VMCNT_CODE) do {                                            \
    bf16x8 aF[4];                                                                                     \
    _Pragma("unroll")                                                                                 \
    for (int m = 0; m < 4; ++m)                                                                       \
        aF[m] = *reinterpret_cast<const bf16x8*>(                                                     \
            &smem[((BUF) * 2 + (H)) * 8192 + ((aRdS[m] ^ ((KQ) * 64)) >> 1)]);                        \
    if (LOADB) {                                                                                      \
        _Pragma("unroll")                                                                             \
        for (int n = 0; n < 4; ++n)                                                                   \
            bF[KQ][n] = *reinterpret_cast<const bf16x8*>(                                             \
                &smem[32768 + ((BUF) * 2 + bHalf) * 8192 + ((bRdS[n] ^ ((KQ) * 64)) >> 1)]);          \
    }                                                                                                 \
    STAGE_CODE;                                                                                       \
    VMCNT_CODE;                                                                                       \
    asm volatile("" ::: "memory");                                                                    \
    __builtin_amdgcn_s_barrier();                                                                     \
    asm volatile("" ::: "memory");                                                                    \
    __builtin_amdgcn_s_setprio(1);                                                                    \
    _Pragma("unroll")                                                                                 \
    for (int m = 0; m < 4; ++m)                                                                       \
        _Pragma("unroll")                                                                             \
        for (int n = 0; n < 4; ++n)                                                                   \
            acc[(H) * 4 + m][n] =                                                                     \
                __builtin_amdgcn_mfma_f32_16x16x32_bf16(aF[m], bF[KQ][n], acc[(H) * 4 + m][n], 0, 0, 0);\
    __builtin_amdgcn_s_setprio(0);                                                                    \
    asm volatile("" ::: "memory");                                                                    \
    __builtin_amdgcn_s_barrier();                                                                     \
    asm volatile("" ::: "memory");                                                                    \
} while (0)

#define PHH(BUF, H, KQ, LOADB, STAGE_CODE, VMCNT_CODE) do {                                           \
    bf16x8 aFh[2];                                                                                    \
    _Pragma("unroll")                                                                                 \
    for (int m = 0; m < 2; ++m)                                                                       \
        aFh[m] = *reinterpret_cast<const bf16x8*>(                                                    \
            &smem[((BUF) * 2 + (H)) * 8192 + ((aRdH[m] ^ ((KQ) * 64)) >> 1)]);                        \
    if (LOADB) {                                                                                      \
        _Pragma("unroll")                                                                             \
        for (int n = 0; n < 4; ++n)                                                                   \
            bF[KQ][n] = *reinterpret_cast<const bf16x8*>(                                             \
                &smem[32768 + ((BUF) * 2 + bHalf) * 8192 + ((bRdS[n] ^ ((KQ) * 64)) >> 1)]);          \
    }                                                                                                 \
    STAGE_CODE;                                                                                       \
    VMCNT_CODE;                                                                                      \
    asm volatile("" ::: "memory");                                                                    \
    __builtin_amdgcn_s_barrier();                                                                     \
    asm volatile("" ::: "memory");                                                                    \
    __builtin_amdgcn_s_setprio(1);                                                                    \
    _Pragma("unroll")                                                                                 \
    for (int m = 0; m < 2; ++m)                                                                       \
        _Pragma("unroll")                                                                             \
        for (int n = 0; n < 4; ++n)                                                                   \
            acch[(H) * 2 + m][n] =                                                                    \
                __builtin_amdgcn_mfma_f32_16x16x32_bf16(aFh[m], bF[KQ][n], acch[(H) * 2 + m][n], 0, 0, 0);\
    __builtin_amdgcn_s_setprio(0);                                                                    \
    asm volatile("" ::: "memory");                                                                    \
    __builtin_amdgcn_s_barrier();                                                                     \
    asm volatile("" ::: "memory");                                                                    \
} while (0)

#define VMC4 asm volatile("s_waitcnt vmcnt(4)" ::: "memory")
#define VMC3 asm volatile("s_waitcnt vmcnt(3)" ::: "memory")
#define VMC0 asm volatile("s_waitcnt vmcnt(0)" ::: "memory")
#define NOVM (void)0

__global__ __launch_bounds__(512, 2) void gemm_gates8(const unsigned short* __restrict__ A,
                                                      const unsigned short* __restrict__ W,
                                                      const float* __restrict__ bias,
                                                      unsigned short* __restrict__ C) {
    constexpr int K = K_DIM;
    constexpr int NT = K / 64;
    constexpr int NI = NT / 2;
    extern __shared__ unsigned short smem[];

    const int tid = threadIdx.x;
    const int bid = blockIdx.x;                 // 768 blocks: 512 full + 256 half
    const int lane = tid & 63;
    const int wid = tid >> 6;
    const int wr = wid >> 2;
    const int wc = wid & 3;
    const int fr = lane & 15;
    const int kb = lane >> 4;
    const int bHalf = wc >> 1;
    const int swzl = (fr & 7) << 4;

    if (bid < 512) {
        const int swz = (bid & 7) * 64 + (bid >> 3);
        const int tm = swz >> 4;
        const int tn = swz & 15;
        const int Arow0 = tm * 256;
        const int Brow0 = tn * 256;

        int aRdS[4], bRdS[4];
#pragma unroll
        for (int m = 0; m < 4; ++m)
            aRdS[m] = (((wr * 64 + m * 16 + fr) * 128) + kb * 16) ^ swzl;
#pragma unroll
        for (int n = 0; n < 4; ++n)
            bRdS[n] = ((((wc & 1) * 64 + n * 16 + fr) * 128) + kb * 16) ^ swzl;

        size_t aSrc[2], bSrc[2];
        int ldsDst[2];
#pragma unroll
        for (int l = 0; l < 2; ++l) {
            const int off = (l * 512 + tid) * 16;
            const int r = off >> 7;
            const int offS = off ^ ((r & 7) << 4);
            const int cb = (offS & 127) >> 1;
            aSrc[l] = (size_t)(Arow0 + r) * K + cb;
            bSrc[l] = (size_t)(Brow0 + r) * K + cb;
            ldsDst[l] = (l * 512 + tid) * 8;
        }

        auto stageA = [&](int buf, int half, int kt) {
#pragma unroll
            for (int l = 0; l < 2; ++l)
                __builtin_amdgcn_global_load_lds(
                    (cg_void*)(A + aSrc[l] + (size_t)half * 128 * K + kt * 64),
                    (lds_void*)(&smem[(buf * 2 + half) * 8192 + ldsDst[l]]), 16, 0, 0);
        };
        auto stageB = [&](int buf, int half, int kt) {
#pragma unroll
            for (int l = 0; l < 2; ++l)
                __builtin_amdgcn_global_load_lds(
                    (cg_void*)(W + bSrc[l] + (size_t)half * 128 * K + kt * 64),
                    (lds_void*)(&smem[32768 + (buf * 2 + half) * 8192 + ldsDst[l]]), 16, 0, 0);
        };

        f32x4 acc[8][4] = {};

        stageA(0, 0, 0); stageA(0, 1, 0); stageB(0, 0, 0); stageB(0, 1, 0);
        stageB(1, 0, 1); stageB(1, 1, 1);
        VMC4;
        asm volatile("" ::: "memory");
        __builtin_amdgcn_s_barrier();
        asm volatile("" ::: "memory");

        for (int i = 0; i < NI; ++i) {
            const int t1 = 2 * i + 1;
            const int t2 = (2 * i + 2) & (NT - 1);
            const int t3 = (2 * i + 3) & (NT - 1);
            bf16x8 bF[2][4];
            PH(0, 0, 0, 1, { stageA(1, 0, t1); stageA(1, 1, t1); }, NOVM);   // P1
            PH(0, 0, 1, 1, ;, NOVM);                                          // P2
            PH(0, 1, 0, 0, { stageA(0, 0, t2); }, NOVM);                      // P3
            PH(0, 1, 1, 0, { stageB(0, 0, t2); }, VMC4);                      // P4
            PH(1, 0, 0, 1, { stageA(0, 1, t2); stageB(0, 1, t2); }, NOVM);    // P5
            PH(1, 0, 1, 1, ;, NOVM);                                          // P6
            PH(1, 1, 0, 0, { stageB(1, 0, t3); }, NOVM);                      // P7
            PH(1, 1, 1, 0, { stageB(1, 1, t3); }, VMC4);                      // P8
        }

        VMC0;
        asm volatile("" ::: "memory");
        __builtin_amdgcn_s_barrier();
        asm volatile("" ::: "memory");

#pragma unroll
        for (int n = 0; n < 4; ++n) {
            const int lcol = wc * 64 + n * 16 + fr;
            const float bvv = bias[Brow0 + lcol];
#pragma unroll
            for (int hh = 0; hh < 2; ++hh)
#pragma unroll
                for (int m = 0; m < 4; ++m) {
                    const int lr0 = wr * 64 + hh * 128 + m * 16 + kb * 4;
#pragma unroll
                    for (int j = 0; j < 4; ++j) {
                        const int lrow = lr0 + j;
                        const int byte = lrow * 512 + ((lcol * 2) ^ ((lrow & 7) << 4));
                        smem[byte >> 1] = f2bf(acc[hh * 4 + m][n][j] + bvv);
                    }
                }
        }
        asm volatile("" ::: "memory");
        __builtin_amdgcn_s_barrier();
        asm volatile("" ::: "memory");
#pragma unroll
        for (int k = 0; k < 16; ++k) {
            const int cid = k * 512 + tid;
            const int row = cid >> 5;
            const int c16 = cid & 31;
            const int byte = row * 512 + ((c16 * 16) ^ ((row & 7) << 4));
            bf16x8 v = *reinterpret_cast<const bf16x8*>(&smem[byte >> 1]);
            *reinterpret_cast<bf16x8*>(&C[(size_t)(Arow0 + row) * NG + Brow0 + c16 * 8]) = v;
        }
    } else {
        const int idx = bid - 512;
        const int sidx = (idx & 7) * 32 + (idx >> 3);
        const int t2i = sidx >> 1;
        const int mhalf = sidx & 1;
        const int tm = t2i >> 2;
        const int tn = 16 + (t2i & 3);
        const int Arow0 = tm * 256 + mhalf * 128;
        const int Brow0 = tn * 256;

        int aRdH[2], bRdS[4];
#pragma unroll
        for (int m = 0; m < 2; ++m)
            aRdH[m] = (((wr * 32 + m * 16 + fr) * 128) + kb * 16) ^ swzl;
#pragma unroll
        for (int n = 0; n < 4; ++n)
            bRdS[n] = ((((wc & 1) * 64 + n * 16 + fr) * 128) + kb * 16) ^ swzl;

        size_t aSrcH;
        {
            const int off = tid * 16;
            const int r = off >> 7;
            const int offS = off ^ ((r & 7) << 4);
            const int cb = (offS & 127) >> 1;
            aSrcH = (size_t)(Arow0 + r) * K + cb;
        }
        size_t bSrc[2];
        int ldsDst[2];
#pragma unroll
        for (int l = 0; l < 2; ++l) {
            const int off = (l * 512 + tid) * 16;
            const int r = off >> 7;
            const int offS = off ^ ((r & 7) << 4);
            const int cb = (offS & 127) >> 1;
            bSrc[l] = (size_t)(Brow0 + r) * K + cb;
            ldsDst[l] = (l * 512 + tid) * 8;
        }

        auto stageAH = [&](int buf, int half, int kt) {
            __builtin_amdgcn_global_load_lds(
                (cg_void*)(A + aSrcH + (size_t)half * 64 * K + kt * 64),
                (lds_void*)(&smem[(buf * 2 + half) * 8192 + tid * 8]), 16, 0, 0);
        };
        auto stageB = [&](int buf, int half, int kt) {
#pragma unroll
            for (int l = 0; l < 2; ++l)
                __builtin_amdgcn_global_load_lds(
                    (cg_void*)(W + bSrc[l] + (size_t)half * 128 * K + kt * 64),
                    (lds_void*)(&smem[32768 + (buf * 2 + half) * 8192 + ldsDst[l]]), 16, 0, 0);
        };

        f32x4 acch[4][4] = {};

        stageAH(0, 0, 0); stageAH(0, 1, 0); stageB(0, 0, 0); stageB(0, 1, 0);
        stageB(1, 0, 1); stageB(1, 1, 1);
        VMC4;
        asm volatile("" ::: "memory");
        __builtin_amdgcn_s_barrier();
        asm volatile("" ::: "memory");

        for (int i = 0; i < NI; ++i) {
            const int t1 = 2 * i + 1;
            const int t2 = (2 * i + 2) & (NT - 1);
            const int t3 = (2 * i + 3) & (NT - 1);
            bf16x8 bF[2][4];
            PHH(0, 0, 0, 1, { stageAH(1, 0, t1); stageAH(1, 1, t1); }, NOVM);   // P1
            PHH(0, 0, 1, 1, ;, NOVM);                                            // P2
            PHH(0, 1, 0, 0, { stageAH(0, 0, t2); }, NOVM);                       // P3
            PHH(0, 1, 1, 0, { stageB(0, 0, t2); }, VMC3);                        // P4
            PHH(1, 0, 0, 1, { stageAH(0, 1, t2); stageB(0, 1, t2); }, NOVM);     // P5
            PHH(1, 0, 1, 1, ;, NOVM);                                            // P6
            PHH(1, 1, 0, 0, { stageB(1, 0, t3); }, NOVM);                        // P7
            PHH(1, 1, 1, 0, { stageB(1, 1, t3); }, VMC4);                        // P8
        }

        VMC0;
        asm volatile("" ::: "memory");
        __builtin_amdgcn_s_barrier();
        asm volatile("" ::: "memory");

#pragma unroll
        for (int n = 0; n < 4; ++n) {
            const int lcol = wc * 64 + n * 16 + fr;
            const float bvv = bias[Brow0 + lcol];
#pragma unroll
            for (int hh = 0; hh < 2; ++hh)
#pragma unroll
                for (int m = 0; m < 2; ++m) {
                    const int lr0 = hh * 64 + wr * 32 + m * 16 + kb * 4;
#pragma unroll
                    for (int j = 0; j < 4; ++j) {
                        const int lrow = lr0 + j;
                        const int byte = lrow * 512 + ((lcol * 2) ^ ((lrow & 7) << 4));
                        smem[byte >> 1] = f2bf(acch[hh * 2 + m][n][j] + bvv);
                    }
                }
        }
        asm volatile("" ::: "memory");
        __builtin_amdgcn_s_barrier();
        asm volatile("" ::: "memory");
#pragma unroll
        for (int k = 0; k < 8; ++k) {
            const int cid = k * 512 + tid;
            const int row = cid >> 5;
            const int c16 = cid & 31;
            const int byte = row * 512 + ((c16 * 16) ^ ((row & 7) << 4));
            bf16x8 v = *reinterpret_cast<const bf16x8*>(&smem[byte >> 1]);
            *reinterpret_cast<bf16x8*>(&C[(size_t)(Arow0 + row) * NG + Brow0 + c16 * 8]) = v;
        }
    }
}

// ---------------- GEMM2: 128x128, 3-slot counted-vmcnt pipeline (R5-verified),
// LDS-staged f32 epilogue (R8-verified) ----------------
__global__ __launch_bounds__(256, 3) void gemm_out3(const unsigned short* __restrict__ A,
                                                    const unsigned short* __restrict__ W,
                                                    const float* __restrict__ bias,
                                                    const unsigned short* __restrict__ gates,
                                                    const float* __restrict__ x, const float* __restrict__ h,
                                                    float* __restrict__ out) {
    constexpr int K = K_DIM;
    constexpr int NTK = K / 32;
    extern __shared__ unsigned short smem[];

    const int tid = threadIdx.x;
    const int bid = blockIdx.x;
    const int swz = (bid & 7) * 64 + (bid >> 3);
    const int tn = swz & 7;
    const int tm = swz >> 3;
    const int Arow0 = tm * 128;
    const int Brow0 = tn * 128;

    const int lane = tid & 63;
    const int wid = tid >> 6;
    const int wr = wid >> 1;
    const int wc = wid & 1;
    const int fr = lane & 15;
    const int kb = lane >> 4;

    int aRd[4], bRd[4];
#pragma unroll
    for (int m = 0; m < 4; ++m) {
        const int row = wr * 64 + m * 16 + fr;
        aRd[m] = ((row >> 1) * 128 + ((((row & 1) * 64) + kb * 16) ^ (((row >> 1) & 7) << 4))) >> 1;
    }
#pragma unroll
    for (int n = 0; n < 4; ++n) {
        const int row = wc * 64 + n * 16 + fr;
        bRd[n] = ((row >> 1) * 128 + ((((row & 1) * 64) + kb * 16) ^ (((row >> 1) & 7) << 4))) >> 1;
    }

    size_t aSrcB[2], bSrcB[2];
#pragma unroll
    for (int l = 0; l < 2; ++l) {
        const int t2 = l * 256 + tid;
        const int line = t2 >> 3;
        const int inB = (t2 & 7) * 16;
        const int inBS = inB ^ ((line & 7) << 4);
        const int row = line * 2 + (inBS >> 6);
        const int col = (inBS & 63) >> 1;
        aSrcB[l] = (size_t)(Arow0 + row) * K + col;
        bSrcB[l] = (size_t)(Brow0 + row) * K + col;
    }

    auto stage = [&](int slot, int kt) {
#pragma unroll
        for (int l = 0; l < 2; ++l)
            __builtin_amdgcn_global_load_lds((cg_void*)(A + aSrcB[l] + kt * 32),
                                             (lds_void*)(&smem[slot * 4096 + (l * 256 + tid) * 8]), 16, 0, 0);
#pragma unroll
        for (int l = 0; l < 2; ++l)
            __builtin_amdgcn_global_load_lds((cg_void*)(W + bSrcB[l] + kt * 32),
                                             (lds_void*)(&smem[12288 + slot * 4096 + (l * 256 + tid) * 8]), 16, 0, 0);
    };

    f32x4 acc[4][4] = {};

    stage(0, 0); stage(1, 1);
    VMC4;
    asm volatile("" ::: "memory");
    __builtin_amdgcn_s_barrier();
    asm volatile("" ::: "memory");

    int sC = 0;
    for (int t = 0; t < NTK; ++t) {
        const int sP = (sC == 0) ? 2 : sC - 1;
        const int kt2 = (t + 2) & (NTK - 1);

        bf16x8 aF[4], bF[4];
#pragma unroll
        for (int m = 0; m < 4; ++m)
            aF[m] = *reinterpret_cast<const bf16x8*>(&smem[sC * 4096 + aRd[m]]);
#pragma unroll
        for (int n = 0; n < 4; ++n)
            bF[n] = *reinterpret_cast<const bf16x8*>(&smem[12288 + sC * 4096 + bRd[n]]);

        stage(sP, kt2);
        VMC4;
        asm volatile("" ::: "memory");
        __builtin_amdgcn_s_barrier();
        asm volatile("" ::: "memory");

        __builtin_amdgcn_s_setprio(1);
#pragma unroll
        for (int m = 0; m < 4; ++m)
#pragma unroll
            for (int n = 0; n < 4; ++n)
                acc[m][n] = __builtin_amdgcn_mfma_f32_16x16x32_bf16(aF[m], bF[n], acc[m][n], 0, 0, 0);
        __builtin_amdgcn_s_setprio(0);
        asm volatile("" ::: "memory");
        __builtin_amdgcn_s_barrier();
        asm volatile("" ::: "memory");

        sC = (sC == 2) ? 0 : sC + 1;
    }

    VMC0;
    asm volatile("" ::: "memory");
    __builtin_amdgcn_s_barrier();
    asm volatile("" ::: "memory");

    float* fsm = reinterpret_cast<float*>(smem);
#pragma unroll
    for (int n = 0; n < 4; ++n) {
        const int lcol = wc * 64 + n * 16 + fr;
        const int c = Brow0 + lcol;
        const float bvv = bias[c];
#pragma unroll
        for (int m = 0; m < 4; ++m) {
            const int lr0 = wr * 64 + m * 16 + kb * 4;
#pragma unroll
            for (int j = 0; j < 4; ++j) {
                const int lrow = lr0 + j;
                const size_t r = (size_t)Arow0 + lrow;
                const float u = tanhf(acc[m][n][j] + bvv);
                const size_t gb = r * NG + c;
                const float g2 = bf2f(gates[gb + 2 * D_DIM]);
                const float g3 = bf2f(gates[gb + 3 * D_DIM]);
                const float g4 = bf2f(gates[gb + 4 * D_DIM]);
                const float mx = fmaxf(fmaxf(g2, g3), g4);
                const float e2 = __expf(g2 - mx), e3 = __expf(g3 - mx), e4 = __expf(g4 - mx);
                const float zi = 1.0f / (e2 + e3 + e4);
                const size_t xi = r * D_DIM + c;
                const float ov = (x[xi] * e2 + h[xi] * e3 + u * e4) * zi;
                const int dw = lrow * 128 + (lcol ^ (((lrow >> 2) & 1) << 4));
                fsm[dw] = ov;
            }
        }
    }
    asm volatile("" ::: "memory");
    __builtin_amdgcn_s_barrier();
    asm volatile("" ::: "memory");

#pragma unroll
    for (int k = 0; k < 16; ++k) {
        const int cid = k * 256 + tid;
        const int row = cid >> 5;
        const int c4 = cid & 31;
        const int dw = row * 128 + ((c4 * 4) ^ (((row >> 2) & 1) << 4));
        float4 v = *reinterpret_cast<const float4*>(&fsm[dw]);
        *reinterpret_cast<float4*>(&out[(size_t)(Arow0 + row) * D_DIM + Brow0 + c4 * 4]) = v;
    }
}

extern "C" void kernel_launch(void* const* d_in, const int* in_sizes, int n_in,
                              void* d_out, int out_size, void* d_ws, size_t ws_size,
                              hipStream_t stream) {
    const float* x    = (const float*)d_in[0];
    const float* h    = (const float*)d_in[1];
    const float* ln_w = (const float*)d_in[2];
    const float* ln_b = (const float*)d_in[3];
    const float* ln2_w= (const float*)d_in[4];
    const float* ln2_b= (const float*)d_in[5];
    const float* Wg   = (const float*)d_in[6];
    const float* bg   = (const float*)d_in[7];
    const float* Wu   = (const float*)d_in[8];
    const float* bu   = (const float*)d_in[9];
    float* out = (float*)d_out;

    char* ws = (char*)d_ws;
    unsigned short* inp   = (unsigned short*)(ws);                                   // [8192][2048] (reused as inp2)
    unsigned short* Wg_b  = (unsigned short*)(ws + 33554432);                        // [5120][2048]
    unsigned short* Wu_b  = (unsigned short*)(ws + 33554432 + 20971520);             // [1024][2048]
    unsigned short* gates = (unsigned short*)(ws + 33554432 + 20971520 + 4194304);   // [8192][5120]

    (void)hipFuncSetAttribute((const void*)gemm_gates8,
                              hipFuncAttributeMaxDynamicSharedMemorySize, 131072);
    (void)hipFuncSetAttribute((const void*)gemm_out3,
                              hipFuncAttributeMaxDynamicSharedMemorySize, 65536);

    const int nCvtBlocks = (5120 * 2048 / 4 + 1024 * 2048 / 4 + 255) / 256;   // 12288
    prep_kernel<<<8192 + nCvtBlocks, 256, 0, stream>>>(x, h, ln_w, ln_b, inp, Wg, Wu, Wg_b, Wu_b);
    gemm_gates8<<<768, 512, 131072, stream>>>(inp, Wg_b, bg, gates);
    gate_ln2_kernel<<<8192, 256, 0, stream>>>(x, h, gates, ln2_w, ln2_b, inp);
    gemm_out3<<<512, 256, 65536, stream>>>(inp, Wu_b, bu, gates, x, h, out);
}